// Round 13
// baseline (280.995 us; speedup 1.0000x reference)
//
#include <hip/hip_runtime.h>
#include <math.h>

// Problem constants (from reference setup_inputs)
#define B_    2
#define N_    5000
#define C_    128
#define E_    65536
#define T_    4
#define TWO_N 10000
#define EP_   81920   // padded CSR capacity per (et,b)

// edge types: (src,dst) node types = (0,0),(1,1),(0,1),(1,0)
// s_t = et & 1 ; d_t = ((et+1)>>1) & 1
// XCD-pin convention: pair be = b*4+et == blockIdx.x & 7 for every kernel
// touching per-pair edge data (count, scatter, yji, aggregate, aggklin).
// CSR entry (8 B): uint2 { p fp32 ; (q_bf16 << 16) | src_u16 }
// xn is kept ONLY as bf16 (xnB); nodedot fused on fp32 accumulators in cp.

__device__ __forceinline__ unsigned short f2bf(float f) {
    unsigned u = __float_as_uint(f);
    u += 0x7fffu + ((u >> 16) & 1u);   // RNE
    return (unsigned short)(u >> 16);
}
__device__ __forceinline__ float bf2f(unsigned short h) {
    return __uint_as_float(((unsigned)h) << 16);
}
// fast tanh via hw exp: ~6 ops vs ~25 for libm tanhf; error ~1e-6 (<< bf16 ulp)
__device__ __forceinline__ float fast_tanh_pos(float x) {   // x >= 0
    float e = __expf(-2.f * x);
    return __fdividef(1.f - e, 1.f + e);
}
__device__ __forceinline__ float fast_tanh(float x) {
    float a = fabsf(x);
    float e = __expf(-2.f * a);
    float t = __fdividef(1.f - e, 1.f + e);
    return copysignf(t, x);
}

typedef __attribute__((ext_vector_type(8))) short bfrag;   // 8 bf16
typedef __attribute__((ext_vector_type(4))) float ffrag;   // 4 fp32 acc
typedef __attribute__((ext_vector_type(8))) unsigned short us8;  // 16B bf16 chunk

__device__ __forceinline__ void split8(const float* __restrict__ p, bfrag& hi, bfrag& lo) {
#pragma unroll
    for (int j = 0; j < 8; ++j) {
        float v = p[j];
        unsigned short h = f2bf(v);
        hi[j] = (short)h;
        lo[j] = (short)f2bf(v - bf2f(h));
    }
}

// Weight slots (each 128x128, B-fragment packed):
// 0-1: proj ; 2-5: Wj[et] ; 6-9: Wi[et] ; 10-13: W1[et] ; 14-17: W2[et] ; 18-19: klin[nt]
#define SLOT(i) ((size_t)(i) * 16384)

__device__ __forceinline__ void zero_acc(ffrag (&acc)[2][8]) {
#pragma unroll
    for (int h = 0; h < 2; ++h)
#pragma unroll
        for (int t = 0; t < 8; ++t) acc[h][t] = (ffrag){0.f, 0.f, 0.f, 0.f};
}

// Split-bf16 MFMA GEMM core, K=128, 4 waves x 32 rows, N=128. fp32 A (cp only).
__device__ __forceinline__ void mfma128(const float* __restrict__ A,
                                        const unsigned short* __restrict__ Whi,
                                        const unsigned short* __restrict__ Wlo,
                                        ffrag (&acc)[2][8], int bx)
{
    const int wave = threadIdx.x >> 6, lane = threadIdx.x & 63;
    const int mloc = lane & 15, quad = lane >> 4;
    const int row0w = bx * 128 + wave * 32;
    int r0 = row0w + mloc;      if (r0 >= N_) r0 = N_ - 1;  // clamp, stores guarded
    int r1 = row0w + 16 + mloc; if (r1 >= N_) r1 = N_ - 1;
#pragma unroll
    for (int s = 0; s < 4; ++s) {
        bfrag a0h, a0l, a1h, a1l;
        split8(A + (size_t)r0 * C_ + s * 32 + quad * 8, a0h, a0l);
        split8(A + (size_t)r1 * C_ + s * 32 + quad * 8, a1h, a1l);
        const unsigned short* pBh = Whi + ((size_t)s * 512 + lane) * 8;
        const unsigned short* pBl = Wlo + ((size_t)s * 512 + lane) * 8;
#pragma unroll
        for (int t = 0; t < 8; ++t) {
            bfrag bh = *(const bfrag*)(pBh + (size_t)t * 512);
            bfrag bl = *(const bfrag*)(pBl + (size_t)t * 512);
            acc[0][t] = __builtin_amdgcn_mfma_f32_16x16x32_bf16(a0h, bh, acc[0][t], 0, 0, 0);
            acc[0][t] = __builtin_amdgcn_mfma_f32_16x16x32_bf16(a0l, bh, acc[0][t], 0, 0, 0);
            acc[0][t] = __builtin_amdgcn_mfma_f32_16x16x32_bf16(a0h, bl, acc[0][t], 0, 0, 0);
            acc[1][t] = __builtin_amdgcn_mfma_f32_16x16x32_bf16(a1h, bh, acc[1][t], 0, 0, 0);
            acc[1][t] = __builtin_amdgcn_mfma_f32_16x16x32_bf16(a1l, bh, acc[1][t], 0, 0, 0);
            acc[1][t] = __builtin_amdgcn_mfma_f32_16x16x32_bf16(a1h, bl, acc[1][t], 0, 0, 0);
        }
    }
}

// bf16-A half-width core: 4 of 8 n-tiles (cols [half*64, half*64+64)).
__device__ __forceinline__ void mfma128_half_bfA(const unsigned short* __restrict__ A,
                                                 const unsigned short* __restrict__ Whi,
                                                 const unsigned short* __restrict__ Wlo,
                                                 ffrag (&acc)[2][4], int bx, int half)
{
    const int wave = threadIdx.x >> 6, lane = threadIdx.x & 63;
    const int mloc = lane & 15, quad = lane >> 4;
    const int row0w = bx * 128 + wave * 32;
    int r0 = row0w + mloc;      if (r0 >= N_) r0 = N_ - 1;
    int r1 = row0w + 16 + mloc; if (r1 >= N_) r1 = N_ - 1;
#pragma unroll
    for (int s = 0; s < 4; ++s) {
        bfrag a0 = *(const bfrag*)(A + (size_t)r0 * C_ + s * 32 + quad * 8);
        bfrag a1 = *(const bfrag*)(A + (size_t)r1 * C_ + s * 32 + quad * 8);
        const unsigned short* pBh = Whi + ((size_t)s * 512 + (size_t)half * 256 + lane) * 8;
        const unsigned short* pBl = Wlo + ((size_t)s * 512 + (size_t)half * 256 + lane) * 8;
#pragma unroll
        for (int t = 0; t < 4; ++t) {
            bfrag bh = *(const bfrag*)(pBh + (size_t)t * 512);
            bfrag bl = *(const bfrag*)(pBl + (size_t)t * 512);
            acc[0][t] = __builtin_amdgcn_mfma_f32_16x16x32_bf16(a0, bh, acc[0][t], 0, 0, 0);
            acc[0][t] = __builtin_amdgcn_mfma_f32_16x16x32_bf16(a0, bl, acc[0][t], 0, 0, 0);
            acc[1][t] = __builtin_amdgcn_mfma_f32_16x16x32_bf16(a1, bh, acc[1][t], 0, 0, 0);
            acc[1][t] = __builtin_amdgcn_mfma_f32_16x16x32_bf16(a1, bl, acc[1][t], 0, 0, 0);
        }
    }
}

#define ZN_ 81028   // count(40000) + cursor(40000) + colsum(1024) + done(4)

// setup: blocks [0,160) pack_w ; [160] pack_L ; [161,163) prep ; [163,243) zero
__global__ __launch_bounds__(256) void setup_kernel(
    const float* __restrict__ proj_w, const float* __restrict__ att_w,
    const float* __restrict__ agg_w, const float* __restrict__ klin_w,
    const float* __restrict__ lin_src, const float* __restrict__ lin_dst,
    const float* __restrict__ eproj_w, const float* __restrict__ eproj_b,
    const float* __restrict__ att_b,
    unsigned short* __restrict__ wh, unsigned short* __restrict__ wl,
    unsigned short* __restrict__ lph, unsigned short* __restrict__ lpl,
    float* __restrict__ v1, float* __restrict__ bias_i, int* __restrict__ zbase)
{
    int blk = blockIdx.x;
    if (blk < 160) {
        int wave = threadIdx.x >> 6, lane = threadIdx.x & 63;
        int unit = blk * 4 + wave;      // 0..639
        int id = unit >> 5;             // slot 0..19
        int st = unit & 31;
        int s = st >> 3, t = st & 7;
        const float* src;
        if (id < 2)       src = proj_w + (size_t)id * 16384;
        else if (id < 6)  src = att_w + (size_t)(id - 2) * 384 * C_;
        else if (id < 10) src = att_w + (size_t)(id - 6) * 384 * C_ + (size_t)128 * C_;
        else if (id < 14) src = agg_w + (size_t)(id - 10) * 256 * C_;
        else if (id < 18) src = agg_w + (size_t)(id - 14) * 256 * C_ + (size_t)128 * C_;
        else              src = klin_w + (size_t)(id - 18) * 16384;
        int mloc = lane & 15, quad = lane >> 4;
        size_t dbase = SLOT(id) + ((size_t)(s * 8 + t) * 64 + lane) * 8;
#pragma unroll
        for (int j = 0; j < 8; ++j) {
            float v = src[(size_t)(s * 32 + quad * 8 + j) * C_ + t * 16 + mloc];
            unsigned short h = f2bf(v);
            wh[dbase + j] = h;
            wl[dbase + j] = f2bf(v - bf2f(h));
        }
    } else if (blk == 160) {
        int s = threadIdx.x >> 6;       // wave = s (0..3)
        int lane = threadIdx.x & 63;
        int mloc = lane & 15, quad = lane >> 4;
        const float* vec = nullptr;
        if (mloc < 8) {
            int nt = mloc >> 2, idx = mloc & 3;
            if (idx == 0)      vec = lin_src + nt * C_;
            else if (idx == 1) vec = lin_src + (nt + 2) * C_;
            else if (idx == 2) vec = lin_dst + nt * C_;
            else               vec = lin_dst + (3 - nt) * C_;
        }
        size_t dbase = ((size_t)(s * 64) + lane) * 8;
#pragma unroll
        for (int j = 0; j < 8; ++j) {
            float v = vec ? vec[s * 32 + quad * 8 + j] : 0.f;
            unsigned short h = f2bf(v);
            lph[dbase + j] = h;
            lpl[dbase + j] = f2bf(v - bf2f(h));
        }
    } else if (blk < 163) {
        int et = (blk - 161) * 2 + (threadIdx.x >> 7);
        int c = threadIdx.x & 127;
        float s1 = 0.f, s0 = 0.f;
        for (int k = 0; k < 128; ++k) {
            float wv = att_w[(size_t)et * 384 * C_ + (size_t)(256 + k) * C_ + c];
            s1 = fmaf(eproj_w[et * C_ + k], wv, s1);
            s0 = fmaf(eproj_b[et * C_ + k], wv, s0);
        }
        v1[et * C_ + c] = s1;
        bias_i[et * C_ + c] = att_b[et * C_ + c] + s0;
    } else {
        int base = (blk - 163) * 1024 + threadIdx.x * 4;
#pragma unroll
        for (int j = 0; j < 4; ++j)
            if (base + j < ZN_) zbase[base + j] = 0;
    }
}

// count + proj(+nodedot) hybrid: blocks [0,512) count (XCD-pinned, 4 edges/thr) ;
// [512,672) proj (emits xnB bf16 + fused nodedot on fp32 accumulators)
__global__ __launch_bounds__(256) void cp_kernel(
    const int* __restrict__ eidx, int* __restrict__ count,
    const float* __restrict__ x,
    const unsigned short* __restrict__ wph, const unsigned short* __restrict__ wpl,
    const float* __restrict__ proj_b,
    const float* __restrict__ lin_src, const float* __restrict__ lin_dst,
    unsigned short* __restrict__ xnB, float* __restrict__ asrc, float* __restrict__ adst)
{
    int blk = blockIdx.x;
    if (blk < 512) {
        int be = blk & 7;             // XCD-pin: pair = b*4+et
        int et = be & 3, b = be >> 2;
        int t4 = (blk >> 3) * 256 + threadIdx.x;   // 0..16383
        size_t ebase = ((size_t)et * B_ + b) * 2 * E_;
        int4 d4 = *(const int4*)(eidx + ebase + E_ + 4 * t4);
        int* cp = count + (size_t)be * N_;
        atomicAdd(&cp[d4.x], 1);
        atomicAdd(&cp[d4.y], 1);
        atomicAdd(&cp[d4.z], 1);
        atomicAdd(&cp[d4.w], 1);
        return;
    }
    int pidx = blk - 512;             // 0..159
    int bx = pidx % 40;
    int nt = (pidx / 40) & 1;
    int b = pidx / 80;
    const float* A = x + ((size_t)b * TWO_N + (size_t)nt * N_) * C_;
    ffrag acc[2][8];
    zero_acc(acc);
    mfma128(A, wph + SLOT(nt), wpl + SLOT(nt), acc, bx);
    unsigned short* out = xnB + (size_t)(b * 2 + nt) * N_ * C_;
    const float* bias = proj_b + nt * C_;
    const int wave = threadIdx.x >> 6, lane = threadIdx.x & 63;
    const int mloc = lane & 15, quad = lane >> 4;
    const int rbase = bx * 128 + wave * 32 + quad * 4;
    // lin columns for the fused nodedot
    const float* lv0 = lin_src + nt * C_;
    const float* lv1 = lin_src + (2 + nt) * C_;
    const float* lv2 = lin_dst + nt * C_;
    const float* lv3 = lin_dst + (3 - nt) * C_;
    float linv[4][8];
#pragma unroll
    for (int t = 0; t < 8; ++t) {
        int col = t * 16 + mloc;
        linv[0][t] = lv0[col]; linv[1][t] = lv1[col];
        linv[2][t] = lv2[col]; linv[3][t] = lv3[col];
    }
    const int et0 = nt, et1 = 2 + nt, et2 = nt, et3 = 3 - nt;
#pragma unroll
    for (int h = 0; h < 2; ++h)
#pragma unroll
        for (int r = 0; r < 4; ++r) {
            int row = rbase + h * 16 + r;
            bool ok = (row < N_);
            float p0 = 0.f, p1 = 0.f, p2 = 0.f, p3 = 0.f;
#pragma unroll
            for (int t = 0; t < 8; ++t) {
                int col = t * 16 + mloc;
                float vv = acc[h][t][r] + bias[col];
                if (ok) out[(size_t)row * C_ + col] = f2bf(vv);
                p0 = fmaf(vv, linv[0][t], p0);
                p1 = fmaf(vv, linv[1][t], p1);
                p2 = fmaf(vv, linv[2][t], p2);
                p3 = fmaf(vv, linv[3][t], p3);
            }
#pragma unroll
            for (int m = 1; m < 16; m <<= 1) {
                p0 += __shfl_xor(p0, m);
                p1 += __shfl_xor(p1, m);
                p2 += __shfl_xor(p2, m);
                p3 += __shfl_xor(p3, m);
            }
            if (mloc == 0 && ok) {
                asrc[(size_t)(b * T_ + et0) * N_ + row] = p0;
                asrc[(size_t)(b * T_ + et1) * N_ + row] = p1;
                adst[(size_t)(b * T_ + et2) * N_ + row] = p2;
                adst[(size_t)(b * T_ + et3) * N_ + row] = p3;
            }
        }
}

// Exclusive scan of 4-aligned strides -> CSR offsets; zero pad slots.
__global__ __launch_bounds__(256) void scan_kernel(const int* __restrict__ count,
                                                   int* __restrict__ offs,
                                                   unsigned int* __restrict__ pwq)
{
    int be = blockIdx.x;
    const int* cnt = count + (size_t)be * N_;
    int* off = offs + (size_t)be * (N_ + 1);
    __shared__ int sums[256];
    int tid = threadIdx.x;
    const int chunk = (N_ + 255) / 256;  // 20
    int lo = tid * chunk, hi = min(lo + chunk, N_);
    int s = 0;
    for (int i = lo; i < hi; ++i) s += (cnt[i] + 3) & ~3;
    sums[tid] = s;
    __syncthreads();
    for (int d = 1; d < 256; d <<= 1) {
        int v = (tid >= d) ? sums[tid - d] : 0;
        __syncthreads();
        sums[tid] += v;
        __syncthreads();
    }
    int run = (tid > 0) ? sums[tid - 1] : 0;
    uint2* ep = (uint2*)pwq;
    for (int i = lo; i < hi; ++i) {
        off[i] = run;
        int c = cnt[i], pc = (c + 3) & ~3;
        for (int k = c; k < pc; ++k)
            ep[(size_t)be * EP_ + run + k] = make_uint2(0u, 0u);
        run += pc;
    }
    if (tid == 255) off[N_] = sums[255];
}

// scatter + yji hybrid: blocks [0,512) scatter (4 edges/thr) ; [512,1792) yji —
// both XCD-pinned by pair (blk & 7 == be).
// yji roles: 0 -> G = interleaved bf16 {Z=xs*(xs@Wj), xs} ; 1 -> Yi (bf16);
// each role split into col-halves (64 cols/block).
__global__ __launch_bounds__(256) void sy_kernel(
    const int* __restrict__ eidx, const float* __restrict__ ew,
    const float* __restrict__ asrc, const float* __restrict__ adst,
    const int* __restrict__ offs, int* __restrict__ cursor,
    unsigned int* __restrict__ pwq,
    const unsigned short* __restrict__ xnB,
    const unsigned short* __restrict__ wph, const unsigned short* __restrict__ wpl,
    const float* __restrict__ bias_i,
    unsigned short* __restrict__ G, unsigned short* __restrict__ YiB)
{
    int blk = blockIdx.x;
    if (blk < 512) {
        int be = blk & 7;             // XCD-pin
        int et = be & 3, b = be >> 2;
        int t4 = (blk >> 3) * 256 + threadIdx.x;   // 0..16383
        size_t ebase = ((size_t)et * B_ + b) * 2 * E_;
        int4 s4 = *(const int4*)(eidx + ebase + 4 * t4);
        int4 d4 = *(const int4*)(eidx + ebase + E_ + 4 * t4);
        float4 w4 = *(const float4*)(ew + ((size_t)et * B_ + b) * E_ + 4 * t4);
        const float* ap = asrc + (size_t)be * N_;
        const float* dp = adst + (size_t)be * N_;
        const int* op = offs + (size_t)be * (N_ + 1);
        int* cp = cursor + (size_t)be * N_;
        uint2* epb = (uint2*)pwq + (size_t)be * EP_;
#pragma unroll
        for (int j = 0; j < 4; ++j) {
            int src = (j == 0) ? s4.x : (j == 1) ? s4.y : (j == 2) ? s4.z : s4.w;
            int dst = (j == 0) ? d4.x : (j == 1) ? d4.y : (j == 2) ? d4.z : d4.w;
            float w = (j == 0) ? w4.x : (j == 1) ? w4.y : (j == 2) ? w4.z : w4.w;
            float al = ap[src] + dp[dst];
            al = (al > 0.f) ? al : 0.2f * al;
            float p = __expf(al);
            int pos = op[dst] + atomicAdd(&cp[dst], 1);
            unsigned int packed = (unsigned int)src | ((unsigned int)f2bf(p * w) << 16);
            epb[pos] = make_uint2(__float_as_uint(p), packed);
        }
        return;
    }
    int yidx = blk - 512;             // 0..1279 ; 512 % 8 == 0 keeps pin aligned
    int be = yidx & 7;                // XCD-pin
    int et = be & 3, b = be >> 2;
    int rest = yidx >> 3;             // 0..159
    int half = rest & 1;
    int role = (rest >> 1) & 1;
    int bx = rest >> 2;               // 0..39
    int s_t = et & 1, d_t = ((et + 1) >> 1) & 1;
    int ntsel = (role == 0) ? s_t : d_t;
    const unsigned short* A = xnB + (size_t)(b * 2 + ntsel) * N_ * C_;
    int slot = (role == 0) ? 2 + et : 6 + et;
    ffrag acc[2][4];
#pragma unroll
    for (int h = 0; h < 2; ++h)
#pragma unroll
        for (int t = 0; t < 4; ++t) acc[h][t] = (ffrag){0.f, 0.f, 0.f, 0.f};
    mfma128_half_bfA(A, wph + SLOT(slot), wpl + SLOT(slot), acc, bx, half);
    const float* bias = bias_i + et * C_;
    const int wave = threadIdx.x >> 6, lane = threadIdx.x & 63;
    const int mloc = lane & 15, quad = lane >> 4;
    const int rbase = bx * 128 + wave * 32 + quad * 4;
#pragma unroll
    for (int h = 0; h < 2; ++h)
#pragma unroll
        for (int r = 0; r < 4; ++r) {
            int row = rbase + h * 16 + r;
            if (row >= N_) continue;
#pragma unroll
            for (int t = 0; t < 4; ++t) {
                int col = (half * 4 + t) * 16 + mloc;
                float v = acc[h][t][r];
                if (role == 0) {
                    float xv = bf2f(A[(size_t)row * C_ + col]);
                    *(ushort2*)(G + ((size_t)be * N_ + row) * 256 + 2 * col) =
                        make_ushort2(f2bf(v * xv), f2bf(xv));
                } else {
                    YiB[((size_t)be * N_ + row) * C_ + col] = f2bf(v + bias[col]);
                }
            }
        }
}

// Segment-softmax aggregation, one wave per (node, et, b), XCD-pinned by pair.
// aggr = (Σ p·Z[s] + Yi'⊙Σ p·xs + v1⊙Σ q·xs) / Σ p, emitted as bf16.
__global__ __launch_bounds__(256) void aggregate_kernel(
    const unsigned short* __restrict__ G, const unsigned short* __restrict__ YiB,
    const float* __restrict__ v1, const unsigned int* __restrict__ pwq,
    const int* __restrict__ offs, unsigned short* __restrict__ aggrB)
{
    int pair = blockIdx.x & 7;                       // = b*T_+et (XCD-pin)
    int n = (blockIdx.x >> 3) * 4 + (threadIdx.x >> 6);
    int et = pair & 3;
    int be = pair;
    int l = threadIdx.x & 63;
    const unsigned short* Gp = G + (size_t)be * N_ * 256;
    int beg = offs[(size_t)be * (N_ + 1) + n];
    int end = offs[(size_t)be * (N_ + 1) + n + 1];
    const unsigned int* ep = pwq + ((size_t)be * EP_ + beg) * 2;
    float a1x = 0.f, a1y = 0.f, a2x = 0.f, a2y = 0.f, a3x = 0.f, a3y = 0.f, denom = 0.f;
    int cnt = end - beg;  // multiple of 4; pads have p=q=0, src=0
    for (int i = 0; i < cnt; i += 4) {
        uint4 u01 = *(const uint4*)(ep + 2 * i);      // entries i, i+1
        uint4 u23 = *(const uint4*)(ep + 2 * i + 4);  // entries i+2, i+3
        float p0 = __uint_as_float(u01.x), q0 = bf2f((unsigned short)(u01.y >> 16));
        float p1 = __uint_as_float(u01.z), q1 = bf2f((unsigned short)(u01.w >> 16));
        float p2 = __uint_as_float(u23.x), q2 = bf2f((unsigned short)(u23.y >> 16));
        float p3 = __uint_as_float(u23.z), q3 = bf2f((unsigned short)(u23.w >> 16));
        int s0 = u01.y & 0xffff, s1 = u01.w & 0xffff;
        int s2 = u23.y & 0xffff, s3 = u23.w & 0xffff;
        ushort4 g0 = *(const ushort4*)(Gp + (size_t)s0 * 256 + 4 * l);
        ushort4 g1 = *(const ushort4*)(Gp + (size_t)s1 * 256 + 4 * l);
        ushort4 g2 = *(const ushort4*)(Gp + (size_t)s2 * 256 + 4 * l);
        ushort4 g3 = *(const ushort4*)(Gp + (size_t)s3 * 256 + 4 * l);
        denom += p0 + p1 + p2 + p3;
        a1x = fmaf(p0, bf2f(g0.x), a1x); a2x = fmaf(p0, bf2f(g0.y), a2x);
        a3x = fmaf(q0, bf2f(g0.y), a3x);
        a1y = fmaf(p0, bf2f(g0.z), a1y); a2y = fmaf(p0, bf2f(g0.w), a2y);
        a3y = fmaf(q0, bf2f(g0.w), a3y);
        a1x = fmaf(p1, bf2f(g1.x), a1x); a2x = fmaf(p1, bf2f(g1.y), a2x);
        a3x = fmaf(q1, bf2f(g1.y), a3x);
        a1y = fmaf(p1, bf2f(g1.z), a1y); a2y = fmaf(p1, bf2f(g1.w), a2y);
        a3y = fmaf(q1, bf2f(g1.w), a3y);
        a1x = fmaf(p2, bf2f(g2.x), a1x); a2x = fmaf(p2, bf2f(g2.y), a2x);
        a3x = fmaf(q2, bf2f(g2.y), a3x);
        a1y = fmaf(p2, bf2f(g2.z), a1y); a2y = fmaf(p2, bf2f(g2.w), a2y);
        a3y = fmaf(q2, bf2f(g2.w), a3y);
        a1x = fmaf(p3, bf2f(g3.x), a1x); a2x = fmaf(p3, bf2f(g3.y), a2x);
        a3x = fmaf(q3, bf2f(g3.y), a3x);
        a1y = fmaf(p3, bf2f(g3.z), a1y); a2y = fmaf(p3, bf2f(g3.w), a2y);
        a3y = fmaf(q3, bf2f(g3.w), a3y);
    }
    ushort2 yiu = *(const ushort2*)(YiB + ((size_t)be * N_ + n) * C_ + 2 * l);
    float2 vv = *(const float2*)(v1 + et * C_ + 2 * l);
    float inv = (denom > 0.f) ? 1.f / denom : 0.f;
    float ox = (a1x + bf2f(yiu.x) * a2x + vv.x * a3x) * inv;
    float oy = (a1y + bf2f(yiu.y) * a2y + vv.y * a3y) * inv;
    *(ushort2*)(aggrB + ((size_t)be * N_ + n) * C_ + 2 * l) = make_ushort2(f2bf(ox), f2bf(oy));
}

#define AGGK_BLOCKS 1280

// Fused (M=32 tiles, each wave owns 16 rows x 64 cols): outs = tanh(relu(
// aggr@W1 + xnB[d_t]@W2 + agg_b)) -> LDS tile -> vectorized copy to outsB;
// then klin GEMM on the tile -> colsum (quad-reduced); last block -> attn.
__global__ __launch_bounds__(256) void aggklin_kernel(
    const unsigned short* __restrict__ aggrB, const unsigned short* __restrict__ xnB,
    const unsigned short* __restrict__ wph, const unsigned short* __restrict__ wpl,
    const float* __restrict__ agg_b, const float* __restrict__ klin_b,
    const float* __restrict__ q, unsigned short* __restrict__ outsB,
    float* __restrict__ colsum, int* __restrict__ done, float* __restrict__ attn)
{
    int blk = blockIdx.x;
    int be = blk & 7, bx = blk >> 3;   // XCD-pin by pair; bx 0..159 (M=32 tiles)
    int et = be & 3, b = be >> 2;
    int d_t = ((et + 1) >> 1) & 1;
    size_t base = (size_t)be * N_ * C_;
    const int wave = threadIdx.x >> 6, lane = threadIdx.x & 63;
    const int mloc = lane & 15, quad = lane >> 4;
    const int wrow = wave & 1, half = wave >> 1;   // row strip / col half per wave
    int r0 = bx * 32 + wrow * 16 + mloc; if (r0 >= N_) r0 = N_ - 1;
    ffrag acc[4];
#pragma unroll
    for (int t = 0; t < 4; ++t) acc[t] = (ffrag){0.f, 0.f, 0.f, 0.f};
    const unsigned short* A1 = aggrB + base + (size_t)r0 * C_;
    const unsigned short* A2 = xnB + (size_t)(b * 2 + d_t) * N_ * C_ + (size_t)r0 * C_;
    const unsigned short* W1h = wph + SLOT(10 + et);
    const unsigned short* W1l = wpl + SLOT(10 + et);
    const unsigned short* W2h = wph + SLOT(14 + et);
    const unsigned short* W2l = wpl + SLOT(14 + et);
#pragma unroll
    for (int s = 0; s < 4; ++s) {
        bfrag a1 = *(const bfrag*)(A1 + s * 32 + quad * 8);
        bfrag a2 = *(const bfrag*)(A2 + s * 32 + quad * 8);
        size_t boff = ((size_t)s * 512 + (size_t)half * 256 + lane) * 8;
#pragma unroll
        for (int t = 0; t < 4; ++t) {
            bfrag b1h = *(const bfrag*)(W1h + boff + (size_t)t * 512);
            bfrag b1l = *(const bfrag*)(W1l + boff + (size_t)t * 512);
            bfrag b2h = *(const bfrag*)(W2h + boff + (size_t)t * 512);
            bfrag b2l = *(const bfrag*)(W2l + boff + (size_t)t * 512);
            acc[t] = __builtin_amdgcn_mfma_f32_16x16x32_bf16(a1, b1h, acc[t], 0, 0, 0);
            acc[t] = __builtin_amdgcn_mfma_f32_16x16x32_bf16(a1, b1l, acc[t], 0, 0, 0);
            acc[t] = __builtin_amdgcn_mfma_f32_16x16x32_bf16(a2, b2h, acc[t], 0, 0, 0);
            acc[t] = __builtin_amdgcn_mfma_f32_16x16x32_bf16(a2, b2l, acc[t], 0, 0, 0);
        }
    }
    __shared__ unsigned short tile[32][136];   // 8.7 KB, +8 pad
    const float* bias = agg_b + et * C_;
#pragma unroll
    for (int r = 0; r < 4; ++r) {
        int lrow = wrow * 16 + quad * 4 + r;
#pragma unroll
        for (int t = 0; t < 4; ++t) {
            int col = (half * 4 + t) * 16 + mloc;
            float v = acc[t][r] + bias[col];
            v = (v > 0.f) ? fast_tanh_pos(v) : 0.f;
            tile[lrow][col] = f2bf(v);
        }
    }
    __syncthreads();
    // vectorized tile -> outsB copy (16B coalesced stores): 512 chunks, 2/thread
    {
        int row0 = bx * 32;
#pragma unroll
        for (int it = 0; it < 2; ++it) {
            int chunk = it * 256 + threadIdx.x;       // 0..511
            int row = chunk >> 4, c8 = (chunk & 15) * 8;
            int grow = row0 + row;
            if (grow < N_)
                *(us8*)(outsB + base + (size_t)grow * C_ + c8) = *(const us8*)&tile[row][c8];
        }
    }
    // second GEMM: klin[nt] on the tile (nt == d_t ; tt = et>=2)
    int nt = d_t, tt = (et >= 2) ? 1 : 0;
    ffrag acc2[4];
#pragma unroll
    for (int t = 0; t < 4; ++t) acc2[t] = (ffrag){0.f, 0.f, 0.f, 0.f};
    const unsigned short* Kh = wph + SLOT(18 + nt);
    const unsigned short* Kl = wpl + SLOT(18 + nt);
    int lr = wrow * 16 + mloc;
#pragma unroll
    for (int s = 0; s < 4; ++s) {
        bfrag a0 = *(const bfrag*)&tile[lr][s * 32 + quad * 8];
        size_t boff = ((size_t)s * 512 + (size_t)half * 256 + lane) * 8;
#pragma unroll
        for (int t = 0; t < 4; ++t) {
            bfrag bh = *(const bfrag*)(Kh + boff + (size_t)t * 512);
            bfrag bl = *(const bfrag*)(Kl + boff + (size_t)t * 512);
            acc2[t] = __builtin_amdgcn_mfma_f32_16x16x32_bf16(a0, bh, acc2[t], 0, 0, 0);
            acc2[t] = __builtin_amdgcn_mfma_f32_16x16x32_bf16(a0, bl, acc2[t], 0, 0, 0);
        }
    }
    __shared__ float cs[128];
    if (threadIdx.x < 128) cs[threadIdx.x] = 0.f;
    __syncthreads();
    const int rbase = bx * 32 + wrow * 16 + quad * 4;
#pragma unroll
    for (int t = 0; t < 4; ++t) {
        int col = (half * 4 + t) * 16 + mloc;
        float bv = klin_b[nt * C_ + col];
        float s = 0.f;
#pragma unroll
        for (int r = 0; r < 4; ++r) {
            int row = rbase + r;
            if (row < N_) s += fast_tanh(acc2[t][r] + bv);
        }
        s += __shfl_xor(s, 16);
        s += __shfl_xor(s, 32);
        if (quad == 0) atomicAdd(&cs[col], s);
    }
    __syncthreads();
    if (threadIdx.x < 128)
        atomicAdd(&colsum[(size_t)((b * 2 + nt) * 2 + tt) * C_ + threadIdx.x], cs[threadIdx.x]);
    // last-block score fusion
    __shared__ int isLast;
    if (threadIdx.x == 0) {
        __threadfence();
        isLast = (atomicAdd(done, 1) == AGGK_BLOCKS - 1) ? 1 : 0;
    }
    __syncthreads();
    if (!isLast) return;
    __shared__ float red[2][2];
    for (int bnt = 0; bnt < 4; ++bnt) {
        int ntl = bnt & 1;
        float v0 = 0.f, v1l = 0.f;
        if (threadIdx.x < 128) {
            int c = threadIdx.x;
            float qc = q[ntl * C_ + c];
            float c0 = atomicAdd(&colsum[(size_t)(bnt * 2 + 0) * C_ + c], 0.f);
            float c1 = atomicAdd(&colsum[(size_t)(bnt * 2 + 1) * C_ + c], 0.f);
            v0 = qc * c0;
            v1l = qc * c1;
        }
#pragma unroll
        for (int m = 32; m > 0; m >>= 1) {
            v0 += __shfl_down(v0, m);
            v1l += __shfl_down(v1l, m);
        }
        if ((threadIdx.x & 63) == 0 && wave < 2) {
            red[wave][0] = v0;
            red[wave][1] = v1l;
        }
        __syncthreads();
        if (threadIdx.x == 0) {
            float s0 = (red[0][0] + red[1][0]) / (float)N_;
            float s1 = (red[0][1] + red[1][1]) / (float)N_;
            float mx = fmaxf(s0, s1);
            float e0 = __expf(s0 - mx), e1 = __expf(s1 - mx);
            float invd = 1.f / (e0 + e1);
            attn[bnt * 2 + 0] = e0 * invd;
            attn[bnt * 2 + 1] = e1 * invd;
        }
        __syncthreads();
    }
}

__global__ void output_kernel(const unsigned short* __restrict__ outsB,
                              const float* __restrict__ attn,
                              float* __restrict__ out)
{
    int idx = blockIdx.x * blockDim.x + threadIdx.x;
    int c4 = idx & 31;
    int row = idx >> 5;
    int b = row / TWO_N;
    int r = row % TWO_N;
    int nt = (r >= N_) ? 1 : 0;
    int n = r - nt * N_;
    int et0 = nt, et1 = 3 - nt;
    float a0 = attn[(b * 2 + nt) * 2 + 0];
    float a1 = attn[(b * 2 + nt) * 2 + 1];
    const ushort4* o0 = (const ushort4*)(outsB + ((size_t)(b * T_ + et0) * N_ + n) * C_);
    const ushort4* o1 = (const ushort4*)(outsB + ((size_t)(b * T_ + et1) * N_ + n) * C_);
    ushort4 u0 = o0[c4], u1 = o1[c4];
    float4 o;
    o.x = a0 * bf2f(u0.x) + a1 * bf2f(u1.x);
    o.y = a0 * bf2f(u0.y) + a1 * bf2f(u1.y);
    o.z = a0 * bf2f(u0.z) + a1 * bf2f(u1.z);
    o.w = a0 * bf2f(u0.w) + a1 * bf2f(u1.w);
    ((float4*)out)[idx] = o;
}

extern "C" void kernel_launch(void* const* d_in, const int* in_sizes, int n_in,
                              void* d_out, int out_size, void* d_ws, size_t ws_size,
                              hipStream_t stream)
{
    const float* x       = (const float*)d_in[0];
    const int*   eidx    = (const int*)d_in[1];
    const float* ew      = (const float*)d_in[2];
    const float* proj_w  = (const float*)d_in[3];
    const float* proj_b  = (const float*)d_in[4];
    const float* q       = (const float*)d_in[5];
    const float* klin_w  = (const float*)d_in[6];
    const float* klin_b  = (const float*)d_in[7];
    const float* lin_src = (const float*)d_in[8];
    const float* lin_dst = (const float*)d_in[9];
    const float* eproj_w = (const float*)d_in[10];
    const float* eproj_b = (const float*)d_in[11];
    const float* agg_w   = (const float*)d_in[12];
    const float* agg_b   = (const float*)d_in[13];
    const float* att_w   = (const float*)d_in[14];
    const float* att_b   = (const float*)d_in[15];

    float* ws = (float*)d_ws;
    size_t o = 0;
    float* xnBf   = ws + o; o += 1280000;   // xn bf16, live proj -> aggklin
    float* GU     = ws + o; o += 5120000;   // G (bf16, sy->aggregate) ∪ outsB (bf16)
    float* YiBf   = ws + o; o += 2560000;   // Yi bf16
    float* aggrBf = ws + o; o += 2560000;   // bf16 aggr
    float* pwqf   = ws + o; o += 2 * 8 * EP_;      // 1,310,720 (uint2 CSR entries)
    float* asrc   = ws + o; o += 40000;
    float* adst   = ws + o; o += 40000;
    float* v1     = ws + o; o += 512;
    float* bias_i = ws + o; o += 512;
    float* attn   = ws + o; o += 16;
    // zeroed-by-setup region (contiguous ints): count, cursor, colsum, done
    int*   count  = (int*)(ws + o); o += 40000;
    int*   cursor = (int*)(ws + o); o += 40000;
    float* colsum = ws + o; o += 1024;
    int*   done   = (int*)(ws + o); o += 4;
    int*   offs   = (int*)(ws + o); o += 40008;
    unsigned short* wph = (unsigned short*)(ws + o); o += 163840;
    unsigned short* wpl = (unsigned short*)(ws + o); o += 163840;
    unsigned short* lph = (unsigned short*)(ws + o); o += 1024;
    unsigned short* lpl = (unsigned short*)(ws + o); o += 1024;
    // total ≈ 13.4M floats ≈ 54 MB

    unsigned short* xnB   = (unsigned short*)xnBf;
    unsigned short* G     = (unsigned short*)GU;
    unsigned short* outsB = (unsigned short*)GU;
    unsigned short* YiB   = (unsigned short*)YiBf;
    unsigned short* aggrB = (unsigned short*)aggrBf;
    unsigned int*   pwq   = (unsigned int*)pwqf;

    setup_kernel<<<dim3(243), 256, 0, stream>>>(proj_w, att_w, agg_w, klin_w,
                                                lin_src, lin_dst, eproj_w, eproj_b,
                                                att_b, wph, wpl, lph, lpl,
                                                v1, bias_i, count);
    cp_kernel<<<dim3(672), 256, 0, stream>>>(eidx, count, x, wph, wpl, proj_b,
                                             lin_src, lin_dst, xnB, asrc, adst);
    scan_kernel<<<dim3(B_ * T_), 256, 0, stream>>>(count, offs, pwq);
    sy_kernel<<<dim3(1792), 256, 0, stream>>>(eidx, ew, asrc, adst, offs, cursor,
                                              pwq, xnB, wph, wpl, bias_i, G, YiB);
    aggregate_kernel<<<dim3(10000), 256, 0, stream>>>(G, YiB, v1, pwq, offs, aggrB);
    aggklin_kernel<<<dim3(AGGK_BLOCKS), 256, 0, stream>>>(aggrB, xnB, wph, wpl, agg_b,
                                                          klin_b, q, outsB, colsum,
                                                          done, attn);
    output_kernel<<<dim3(2500), 256, 0, stream>>>(outsB, attn, (float*)d_out);
}

// Round 14
// 259.518 us; speedup vs baseline: 1.0828x; 1.0828x over previous
//
#include <hip/hip_runtime.h>
#include <math.h>

// Problem constants (from reference setup_inputs)
#define B_    2
#define N_    5000
#define C_    128
#define E_    65536
#define T_    4
#define TWO_N 10000
#define EP_   81920   // padded CSR capacity per (et,b)

// edge types: (src,dst) node types = (0,0),(1,1),(0,1),(1,0)
// s_t = et & 1 ; d_t = ((et+1)>>1) & 1
// XCD-pin convention: pair be = b*4+et == blockIdx.x & 7 for every kernel
// touching per-pair edge data (count, scatter, yji, aggregate, aggklin).
// CSR entry (8 B): uint2 { p fp32 ; (q_bf16 << 16) | src_u16 }
// xn is kept ONLY as bf16 (xnB); nodedot fused on fp32 accumulators in cp.
// R13 lesson: aggklin is L2-weight-load bound, NOT occupancy bound (M=32 split
// raised occupancy 22->38% but regressed 44->59us). R14: M=64 + hi-only weights.

__device__ __forceinline__ unsigned short f2bf(float f) {
    unsigned u = __float_as_uint(f);
    u += 0x7fffu + ((u >> 16) & 1u);   // RNE
    return (unsigned short)(u >> 16);
}
__device__ __forceinline__ float bf2f(unsigned short h) {
    return __uint_as_float(((unsigned)h) << 16);
}
// fast tanh via hw exp: ~6 ops vs ~25 for libm tanhf; error ~1e-6 (<< bf16 ulp)
__device__ __forceinline__ float fast_tanh_pos(float x) {   // x >= 0
    float e = __expf(-2.f * x);
    return __fdividef(1.f - e, 1.f + e);
}
__device__ __forceinline__ float fast_tanh(float x) {
    float a = fabsf(x);
    float e = __expf(-2.f * a);
    float t = __fdividef(1.f - e, 1.f + e);
    return copysignf(t, x);
}

typedef __attribute__((ext_vector_type(8))) short bfrag;   // 8 bf16
typedef __attribute__((ext_vector_type(4))) float ffrag;   // 4 fp32 acc
typedef __attribute__((ext_vector_type(8))) unsigned short us8;  // 16B bf16 chunk

__device__ __forceinline__ void split8(const float* __restrict__ p, bfrag& hi, bfrag& lo) {
#pragma unroll
    for (int j = 0; j < 8; ++j) {
        float v = p[j];
        unsigned short h = f2bf(v);
        hi[j] = (short)h;
        lo[j] = (short)f2bf(v - bf2f(h));
    }
}

// Weight slots (each 128x128, B-fragment packed):
// 0-1: proj ; 2-5: Wj[et] ; 6-9: Wi[et] ; 10-13: W1[et] ; 14-17: W2[et] ; 18-19: klin[nt]
#define SLOT(i) ((size_t)(i) * 16384)

__device__ __forceinline__ void zero_acc(ffrag (&acc)[2][8]) {
#pragma unroll
    for (int h = 0; h < 2; ++h)
#pragma unroll
        for (int t = 0; t < 8; ++t) acc[h][t] = (ffrag){0.f, 0.f, 0.f, 0.f};
}

// Split-bf16 MFMA GEMM core, K=128, 4 waves x 32 rows, N=128. fp32 A (cp only).
__device__ __forceinline__ void mfma128(const float* __restrict__ A,
                                        const unsigned short* __restrict__ Whi,
                                        const unsigned short* __restrict__ Wlo,
                                        ffrag (&acc)[2][8], int bx)
{
    const int wave = threadIdx.x >> 6, lane = threadIdx.x & 63;
    const int mloc = lane & 15, quad = lane >> 4;
    const int row0w = bx * 128 + wave * 32;
    int r0 = row0w + mloc;      if (r0 >= N_) r0 = N_ - 1;  // clamp, stores guarded
    int r1 = row0w + 16 + mloc; if (r1 >= N_) r1 = N_ - 1;
#pragma unroll
    for (int s = 0; s < 4; ++s) {
        bfrag a0h, a0l, a1h, a1l;
        split8(A + (size_t)r0 * C_ + s * 32 + quad * 8, a0h, a0l);
        split8(A + (size_t)r1 * C_ + s * 32 + quad * 8, a1h, a1l);
        const unsigned short* pBh = Whi + ((size_t)s * 512 + lane) * 8;
        const unsigned short* pBl = Wlo + ((size_t)s * 512 + lane) * 8;
#pragma unroll
        for (int t = 0; t < 8; ++t) {
            bfrag bh = *(const bfrag*)(pBh + (size_t)t * 512);
            bfrag bl = *(const bfrag*)(pBl + (size_t)t * 512);
            acc[0][t] = __builtin_amdgcn_mfma_f32_16x16x32_bf16(a0h, bh, acc[0][t], 0, 0, 0);
            acc[0][t] = __builtin_amdgcn_mfma_f32_16x16x32_bf16(a0l, bh, acc[0][t], 0, 0, 0);
            acc[0][t] = __builtin_amdgcn_mfma_f32_16x16x32_bf16(a0h, bl, acc[0][t], 0, 0, 0);
            acc[1][t] = __builtin_amdgcn_mfma_f32_16x16x32_bf16(a1h, bh, acc[1][t], 0, 0, 0);
            acc[1][t] = __builtin_amdgcn_mfma_f32_16x16x32_bf16(a1l, bh, acc[1][t], 0, 0, 0);
            acc[1][t] = __builtin_amdgcn_mfma_f32_16x16x32_bf16(a1h, bl, acc[1][t], 0, 0, 0);
        }
    }
}

// bf16-A half-width core: 4 of 8 n-tiles (cols [half*64, half*64+64)).
__device__ __forceinline__ void mfma128_half_bfA(const unsigned short* __restrict__ A,
                                                 const unsigned short* __restrict__ Whi,
                                                 const unsigned short* __restrict__ Wlo,
                                                 ffrag (&acc)[2][4], int bx, int half)
{
    const int wave = threadIdx.x >> 6, lane = threadIdx.x & 63;
    const int mloc = lane & 15, quad = lane >> 4;
    const int row0w = bx * 128 + wave * 32;
    int r0 = row0w + mloc;      if (r0 >= N_) r0 = N_ - 1;
    int r1 = row0w + 16 + mloc; if (r1 >= N_) r1 = N_ - 1;
#pragma unroll
    for (int s = 0; s < 4; ++s) {
        bfrag a0 = *(const bfrag*)(A + (size_t)r0 * C_ + s * 32 + quad * 8);
        bfrag a1 = *(const bfrag*)(A + (size_t)r1 * C_ + s * 32 + quad * 8);
        const unsigned short* pBh = Whi + ((size_t)s * 512 + (size_t)half * 256 + lane) * 8;
        const unsigned short* pBl = Wlo + ((size_t)s * 512 + (size_t)half * 256 + lane) * 8;
#pragma unroll
        for (int t = 0; t < 4; ++t) {
            bfrag bh = *(const bfrag*)(pBh + (size_t)t * 512);
            bfrag bl = *(const bfrag*)(pBl + (size_t)t * 512);
            acc[0][t] = __builtin_amdgcn_mfma_f32_16x16x32_bf16(a0, bh, acc[0][t], 0, 0, 0);
            acc[0][t] = __builtin_amdgcn_mfma_f32_16x16x32_bf16(a0, bl, acc[0][t], 0, 0, 0);
            acc[1][t] = __builtin_amdgcn_mfma_f32_16x16x32_bf16(a1, bh, acc[1][t], 0, 0, 0);
            acc[1][t] = __builtin_amdgcn_mfma_f32_16x16x32_bf16(a1, bl, acc[1][t], 0, 0, 0);
        }
    }
}

// M=64 bf16-A core, HI-ONLY weights: D = A @ Wh  (weight-lo dropped; used in
// aggklin where the error is damped by tanh / softmax — see R14 notes).
__device__ __forceinline__ void mfma64_bfA_hi(const unsigned short* __restrict__ A,
                                              const unsigned short* __restrict__ Whi,
                                              ffrag (&acc)[8], int bx)
{
    const int wave = threadIdx.x >> 6, lane = threadIdx.x & 63;
    const int mloc = lane & 15, quad = lane >> 4;
    int r0 = bx * 64 + wave * 16 + mloc; if (r0 >= N_) r0 = N_ - 1;
#pragma unroll
    for (int s = 0; s < 4; ++s) {
        bfrag a0 = *(const bfrag*)(A + (size_t)r0 * C_ + s * 32 + quad * 8);
        const unsigned short* pBh = Whi + ((size_t)s * 512 + lane) * 8;
#pragma unroll
        for (int t = 0; t < 8; ++t) {
            bfrag bh = *(const bfrag*)(pBh + (size_t)t * 512);
            acc[t] = __builtin_amdgcn_mfma_f32_16x16x32_bf16(a0, bh, acc[t], 0, 0, 0);
        }
    }
}

#define ZN_ 81028   // count(40000) + cursor(40000) + colsum(1024) + done(4)

// setup: blocks [0,160) pack_w ; [160] pack_L ; [161,163) prep ; [163,243) zero
__global__ __launch_bounds__(256) void setup_kernel(
    const float* __restrict__ proj_w, const float* __restrict__ att_w,
    const float* __restrict__ agg_w, const float* __restrict__ klin_w,
    const float* __restrict__ lin_src, const float* __restrict__ lin_dst,
    const float* __restrict__ eproj_w, const float* __restrict__ eproj_b,
    const float* __restrict__ att_b,
    unsigned short* __restrict__ wh, unsigned short* __restrict__ wl,
    unsigned short* __restrict__ lph, unsigned short* __restrict__ lpl,
    float* __restrict__ v1, float* __restrict__ bias_i, int* __restrict__ zbase)
{
    int blk = blockIdx.x;
    if (blk < 160) {
        int wave = threadIdx.x >> 6, lane = threadIdx.x & 63;
        int unit = blk * 4 + wave;      // 0..639
        int id = unit >> 5;             // slot 0..19
        int st = unit & 31;
        int s = st >> 3, t = st & 7;
        const float* src;
        if (id < 2)       src = proj_w + (size_t)id * 16384;
        else if (id < 6)  src = att_w + (size_t)(id - 2) * 384 * C_;
        else if (id < 10) src = att_w + (size_t)(id - 6) * 384 * C_ + (size_t)128 * C_;
        else if (id < 14) src = agg_w + (size_t)(id - 10) * 256 * C_;
        else if (id < 18) src = agg_w + (size_t)(id - 14) * 256 * C_ + (size_t)128 * C_;
        else              src = klin_w + (size_t)(id - 18) * 16384;
        int mloc = lane & 15, quad = lane >> 4;
        size_t dbase = SLOT(id) + ((size_t)(s * 8 + t) * 64 + lane) * 8;
#pragma unroll
        for (int j = 0; j < 8; ++j) {
            float v = src[(size_t)(s * 32 + quad * 8 + j) * C_ + t * 16 + mloc];
            unsigned short h = f2bf(v);
            wh[dbase + j] = h;
            wl[dbase + j] = f2bf(v - bf2f(h));
        }
    } else if (blk == 160) {
        int s = threadIdx.x >> 6;       // wave = s (0..3)
        int lane = threadIdx.x & 63;
        int mloc = lane & 15, quad = lane >> 4;
        const float* vec = nullptr;
        if (mloc < 8) {
            int nt = mloc >> 2, idx = mloc & 3;
            if (idx == 0)      vec = lin_src + nt * C_;
            else if (idx == 1) vec = lin_src + (nt + 2) * C_;
            else if (idx == 2) vec = lin_dst + nt * C_;
            else               vec = lin_dst + (3 - nt) * C_;
        }
        size_t dbase = ((size_t)(s * 64) + lane) * 8;
#pragma unroll
        for (int j = 0; j < 8; ++j) {
            float v = vec ? vec[s * 32 + quad * 8 + j] : 0.f;
            unsigned short h = f2bf(v);
            lph[dbase + j] = h;
            lpl[dbase + j] = f2bf(v - bf2f(h));
        }
    } else if (blk < 163) {
        int et = (blk - 161) * 2 + (threadIdx.x >> 7);
        int c = threadIdx.x & 127;
        float s1 = 0.f, s0 = 0.f;
        for (int k = 0; k < 128; ++k) {
            float wv = att_w[(size_t)et * 384 * C_ + (size_t)(256 + k) * C_ + c];
            s1 = fmaf(eproj_w[et * C_ + k], wv, s1);
            s0 = fmaf(eproj_b[et * C_ + k], wv, s0);
        }
        v1[et * C_ + c] = s1;
        bias_i[et * C_ + c] = att_b[et * C_ + c] + s0;
    } else {
        int base = (blk - 163) * 1024 + threadIdx.x * 4;
#pragma unroll
        for (int j = 0; j < 4; ++j)
            if (base + j < ZN_) zbase[base + j] = 0;
    }
}

// count + proj(+nodedot) hybrid: blocks [0,512) count (XCD-pinned, 4 edges/thr) ;
// [512,672) proj (emits xnB bf16 + fused nodedot on fp32 accumulators)
__global__ __launch_bounds__(256) void cp_kernel(
    const int* __restrict__ eidx, int* __restrict__ count,
    const float* __restrict__ x,
    const unsigned short* __restrict__ wph, const unsigned short* __restrict__ wpl,
    const float* __restrict__ proj_b,
    const float* __restrict__ lin_src, const float* __restrict__ lin_dst,
    unsigned short* __restrict__ xnB, float* __restrict__ asrc, float* __restrict__ adst)
{
    int blk = blockIdx.x;
    if (blk < 512) {
        int be = blk & 7;             // XCD-pin: pair = b*4+et
        int et = be & 3, b = be >> 2;
        int t4 = (blk >> 3) * 256 + threadIdx.x;   // 0..16383
        size_t ebase = ((size_t)et * B_ + b) * 2 * E_;
        int4 d4 = *(const int4*)(eidx + ebase + E_ + 4 * t4);
        int* cp = count + (size_t)be * N_;
        atomicAdd(&cp[d4.x], 1);
        atomicAdd(&cp[d4.y], 1);
        atomicAdd(&cp[d4.z], 1);
        atomicAdd(&cp[d4.w], 1);
        return;
    }
    int pidx = blk - 512;             // 0..159
    int bx = pidx % 40;
    int nt = (pidx / 40) & 1;
    int b = pidx / 80;
    const float* A = x + ((size_t)b * TWO_N + (size_t)nt * N_) * C_;
    ffrag acc[2][8];
    zero_acc(acc);
    mfma128(A, wph + SLOT(nt), wpl + SLOT(nt), acc, bx);
    unsigned short* out = xnB + (size_t)(b * 2 + nt) * N_ * C_;
    const float* bias = proj_b + nt * C_;
    const int wave = threadIdx.x >> 6, lane = threadIdx.x & 63;
    const int mloc = lane & 15, quad = lane >> 4;
    const int rbase = bx * 128 + wave * 32 + quad * 4;
    // lin columns for the fused nodedot
    const float* lv0 = lin_src + nt * C_;
    const float* lv1 = lin_src + (2 + nt) * C_;
    const float* lv2 = lin_dst + nt * C_;
    const float* lv3 = lin_dst + (3 - nt) * C_;
    float linv[4][8];
#pragma unroll
    for (int t = 0; t < 8; ++t) {
        int col = t * 16 + mloc;
        linv[0][t] = lv0[col]; linv[1][t] = lv1[col];
        linv[2][t] = lv2[col]; linv[3][t] = lv3[col];
    }
    const int et0 = nt, et1 = 2 + nt, et2 = nt, et3 = 3 - nt;
#pragma unroll
    for (int h = 0; h < 2; ++h)
#pragma unroll
        for (int r = 0; r < 4; ++r) {
            int row = rbase + h * 16 + r;
            bool ok = (row < N_);
            float p0 = 0.f, p1 = 0.f, p2 = 0.f, p3 = 0.f;
#pragma unroll
            for (int t = 0; t < 8; ++t) {
                int col = t * 16 + mloc;
                float vv = acc[h][t][r] + bias[col];
                if (ok) out[(size_t)row * C_ + col] = f2bf(vv);
                p0 = fmaf(vv, linv[0][t], p0);
                p1 = fmaf(vv, linv[1][t], p1);
                p2 = fmaf(vv, linv[2][t], p2);
                p3 = fmaf(vv, linv[3][t], p3);
            }
#pragma unroll
            for (int m = 1; m < 16; m <<= 1) {
                p0 += __shfl_xor(p0, m);
                p1 += __shfl_xor(p1, m);
                p2 += __shfl_xor(p2, m);
                p3 += __shfl_xor(p3, m);
            }
            if (mloc == 0 && ok) {
                asrc[(size_t)(b * T_ + et0) * N_ + row] = p0;
                asrc[(size_t)(b * T_ + et1) * N_ + row] = p1;
                adst[(size_t)(b * T_ + et2) * N_ + row] = p2;
                adst[(size_t)(b * T_ + et3) * N_ + row] = p3;
            }
        }
}

// Exclusive scan of 4-aligned strides -> CSR offsets; zero pad slots.
__global__ __launch_bounds__(256) void scan_kernel(const int* __restrict__ count,
                                                   int* __restrict__ offs,
                                                   unsigned int* __restrict__ pwq)
{
    int be = blockIdx.x;
    const int* cnt = count + (size_t)be * N_;
    int* off = offs + (size_t)be * (N_ + 1);
    __shared__ int sums[256];
    int tid = threadIdx.x;
    const int chunk = (N_ + 255) / 256;  // 20
    int lo = tid * chunk, hi = min(lo + chunk, N_);
    int s = 0;
    for (int i = lo; i < hi; ++i) s += (cnt[i] + 3) & ~3;
    sums[tid] = s;
    __syncthreads();
    for (int d = 1; d < 256; d <<= 1) {
        int v = (tid >= d) ? sums[tid - d] : 0;
        __syncthreads();
        sums[tid] += v;
        __syncthreads();
    }
    int run = (tid > 0) ? sums[tid - 1] : 0;
    uint2* ep = (uint2*)pwq;
    for (int i = lo; i < hi; ++i) {
        off[i] = run;
        int c = cnt[i], pc = (c + 3) & ~3;
        for (int k = c; k < pc; ++k)
            ep[(size_t)be * EP_ + run + k] = make_uint2(0u, 0u);
        run += pc;
    }
    if (tid == 255) off[N_] = sums[255];
}

// scatter + yji hybrid: blocks [0,512) scatter (4 edges/thr) ; [512,1792) yji —
// both XCD-pinned by pair (blk & 7 == be).
// yji roles: 0 -> G = interleaved bf16 {Z=xs*(xs@Wj), xs} ; 1 -> Yi (bf16);
// each role split into col-halves (64 cols/block).
__global__ __launch_bounds__(256) void sy_kernel(
    const int* __restrict__ eidx, const float* __restrict__ ew,
    const float* __restrict__ asrc, const float* __restrict__ adst,
    const int* __restrict__ offs, int* __restrict__ cursor,
    unsigned int* __restrict__ pwq,
    const unsigned short* __restrict__ xnB,
    const unsigned short* __restrict__ wph, const unsigned short* __restrict__ wpl,
    const float* __restrict__ bias_i,
    unsigned short* __restrict__ G, unsigned short* __restrict__ YiB)
{
    int blk = blockIdx.x;
    if (blk < 512) {
        int be = blk & 7;             // XCD-pin
        int et = be & 3, b = be >> 2;
        int t4 = (blk >> 3) * 256 + threadIdx.x;   // 0..16383
        size_t ebase = ((size_t)et * B_ + b) * 2 * E_;
        int4 s4 = *(const int4*)(eidx + ebase + 4 * t4);
        int4 d4 = *(const int4*)(eidx + ebase + E_ + 4 * t4);
        float4 w4 = *(const float4*)(ew + ((size_t)et * B_ + b) * E_ + 4 * t4);
        const float* ap = asrc + (size_t)be * N_;
        const float* dp = adst + (size_t)be * N_;
        const int* op = offs + (size_t)be * (N_ + 1);
        int* cp = cursor + (size_t)be * N_;
        uint2* epb = (uint2*)pwq + (size_t)be * EP_;
#pragma unroll
        for (int j = 0; j < 4; ++j) {
            int src = (j == 0) ? s4.x : (j == 1) ? s4.y : (j == 2) ? s4.z : s4.w;
            int dst = (j == 0) ? d4.x : (j == 1) ? d4.y : (j == 2) ? d4.z : d4.w;
            float w = (j == 0) ? w4.x : (j == 1) ? w4.y : (j == 2) ? w4.z : w4.w;
            float al = ap[src] + dp[dst];
            al = (al > 0.f) ? al : 0.2f * al;
            float p = __expf(al);
            int pos = op[dst] + atomicAdd(&cp[dst], 1);
            unsigned int packed = (unsigned int)src | ((unsigned int)f2bf(p * w) << 16);
            epb[pos] = make_uint2(__float_as_uint(p), packed);
        }
        return;
    }
    int yidx = blk - 512;             // 0..1279 ; 512 % 8 == 0 keeps pin aligned
    int be = yidx & 7;                // XCD-pin
    int et = be & 3, b = be >> 2;
    int rest = yidx >> 3;             // 0..159
    int half = rest & 1;
    int role = (rest >> 1) & 1;
    int bx = rest >> 2;               // 0..39
    int s_t = et & 1, d_t = ((et + 1) >> 1) & 1;
    int ntsel = (role == 0) ? s_t : d_t;
    const unsigned short* A = xnB + (size_t)(b * 2 + ntsel) * N_ * C_;
    int slot = (role == 0) ? 2 + et : 6 + et;
    ffrag acc[2][4];
#pragma unroll
    for (int h = 0; h < 2; ++h)
#pragma unroll
        for (int t = 0; t < 4; ++t) acc[h][t] = (ffrag){0.f, 0.f, 0.f, 0.f};
    mfma128_half_bfA(A, wph + SLOT(slot), wpl + SLOT(slot), acc, bx, half);
    const float* bias = bias_i + et * C_;
    const int wave = threadIdx.x >> 6, lane = threadIdx.x & 63;
    const int mloc = lane & 15, quad = lane >> 4;
    const int rbase = bx * 128 + wave * 32 + quad * 4;
#pragma unroll
    for (int h = 0; h < 2; ++h)
#pragma unroll
        for (int r = 0; r < 4; ++r) {
            int row = rbase + h * 16 + r;
            if (row >= N_) continue;
#pragma unroll
            for (int t = 0; t < 4; ++t) {
                int col = (half * 4 + t) * 16 + mloc;
                float v = acc[h][t][r];
                if (role == 0) {
                    float xv = bf2f(A[(size_t)row * C_ + col]);
                    *(ushort2*)(G + ((size_t)be * N_ + row) * 256 + 2 * col) =
                        make_ushort2(f2bf(v * xv), f2bf(xv));
                } else {
                    YiB[((size_t)be * N_ + row) * C_ + col] = f2bf(v + bias[col]);
                }
            }
        }
}

// Segment-softmax aggregation, one wave per (node, et, b), XCD-pinned by pair.
// aggr = (Σ p·Z[s] + Yi'⊙Σ p·xs + v1⊙Σ q·xs) / Σ p, emitted as bf16.
__global__ __launch_bounds__(256) void aggregate_kernel(
    const unsigned short* __restrict__ G, const unsigned short* __restrict__ YiB,
    const float* __restrict__ v1, const unsigned int* __restrict__ pwq,
    const int* __restrict__ offs, unsigned short* __restrict__ aggrB)
{
    int pair = blockIdx.x & 7;                       // = b*T_+et (XCD-pin)
    int n = (blockIdx.x >> 3) * 4 + (threadIdx.x >> 6);
    int et = pair & 3;
    int be = pair;
    int l = threadIdx.x & 63;
    const unsigned short* Gp = G + (size_t)be * N_ * 256;
    int beg = offs[(size_t)be * (N_ + 1) + n];
    int end = offs[(size_t)be * (N_ + 1) + n + 1];
    const unsigned int* ep = pwq + ((size_t)be * EP_ + beg) * 2;
    float a1x = 0.f, a1y = 0.f, a2x = 0.f, a2y = 0.f, a3x = 0.f, a3y = 0.f, denom = 0.f;
    int cnt = end - beg;  // multiple of 4; pads have p=q=0, src=0
    for (int i = 0; i < cnt; i += 4) {
        uint4 u01 = *(const uint4*)(ep + 2 * i);      // entries i, i+1
        uint4 u23 = *(const uint4*)(ep + 2 * i + 4);  // entries i+2, i+3
        float p0 = __uint_as_float(u01.x), q0 = bf2f((unsigned short)(u01.y >> 16));
        float p1 = __uint_as_float(u01.z), q1 = bf2f((unsigned short)(u01.w >> 16));
        float p2 = __uint_as_float(u23.x), q2 = bf2f((unsigned short)(u23.y >> 16));
        float p3 = __uint_as_float(u23.z), q3 = bf2f((unsigned short)(u23.w >> 16));
        int s0 = u01.y & 0xffff, s1 = u01.w & 0xffff;
        int s2 = u23.y & 0xffff, s3 = u23.w & 0xffff;
        ushort4 g0 = *(const ushort4*)(Gp + (size_t)s0 * 256 + 4 * l);
        ushort4 g1 = *(const ushort4*)(Gp + (size_t)s1 * 256 + 4 * l);
        ushort4 g2 = *(const ushort4*)(Gp + (size_t)s2 * 256 + 4 * l);
        ushort4 g3 = *(const ushort4*)(Gp + (size_t)s3 * 256 + 4 * l);
        denom += p0 + p1 + p2 + p3;
        a1x = fmaf(p0, bf2f(g0.x), a1x); a2x = fmaf(p0, bf2f(g0.y), a2x);
        a3x = fmaf(q0, bf2f(g0.y), a3x);
        a1y = fmaf(p0, bf2f(g0.z), a1y); a2y = fmaf(p0, bf2f(g0.w), a2y);
        a3y = fmaf(q0, bf2f(g0.w), a3y);
        a1x = fmaf(p1, bf2f(g1.x), a1x); a2x = fmaf(p1, bf2f(g1.y), a2x);
        a3x = fmaf(q1, bf2f(g1.y), a3x);
        a1y = fmaf(p1, bf2f(g1.z), a1y); a2y = fmaf(p1, bf2f(g1.w), a2y);
        a3y = fmaf(q1, bf2f(g1.w), a3y);
        a1x = fmaf(p2, bf2f(g2.x), a1x); a2x = fmaf(p2, bf2f(g2.y), a2x);
        a3x = fmaf(q2, bf2f(g2.y), a3x);
        a1y = fmaf(p2, bf2f(g2.z), a1y); a2y = fmaf(p2, bf2f(g2.w), a2y);
        a3y = fmaf(q2, bf2f(g2.w), a3y);
        a1x = fmaf(p3, bf2f(g3.x), a1x); a2x = fmaf(p3, bf2f(g3.y), a2x);
        a3x = fmaf(q3, bf2f(g3.y), a3x);
        a1y = fmaf(p3, bf2f(g3.z), a1y); a2y = fmaf(p3, bf2f(g3.w), a2y);
        a3y = fmaf(q3, bf2f(g3.w), a3y);
    }
    ushort2 yiu = *(const ushort2*)(YiB + ((size_t)be * N_ + n) * C_ + 2 * l);
    float2 vv = *(const float2*)(v1 + et * C_ + 2 * l);
    float inv = (denom > 0.f) ? 1.f / denom : 0.f;
    float ox = (a1x + bf2f(yiu.x) * a2x + vv.x * a3x) * inv;
    float oy = (a1y + bf2f(yiu.y) * a2y + vv.y * a3y) * inv;
    *(ushort2*)(aggrB + ((size_t)be * N_ + n) * C_ + 2 * l) = make_ushort2(f2bf(ox), f2bf(oy));
}

#define AGGK_BLOCKS 640

// Fused (M=64 tiles, hi-only weights): outs = tanh(relu(aggr@W1 + xnB[d_t]@W2
// + agg_b)) -> LDS tile -> vectorized copy to outsB; then klin GEMM on the
// tile -> colsum (quad-reduced); last block -> attn.
__global__ __launch_bounds__(256) void aggklin_kernel(
    const unsigned short* __restrict__ aggrB, const unsigned short* __restrict__ xnB,
    const unsigned short* __restrict__ wph,
    const float* __restrict__ agg_b, const float* __restrict__ klin_b,
    const float* __restrict__ q, unsigned short* __restrict__ outsB,
    float* __restrict__ colsum, int* __restrict__ done, float* __restrict__ attn)
{
    int blk = blockIdx.x;
    int be = blk & 7, bx = blk >> 3;   // XCD-pin by pair; bx 0..79 (M=64 tiles)
    int et = be & 3, b = be >> 2;
    int d_t = ((et + 1) >> 1) & 1;
    size_t base = (size_t)be * N_ * C_;
    ffrag acc[8];
#pragma unroll
    for (int t = 0; t < 8; ++t) acc[t] = (ffrag){0.f, 0.f, 0.f, 0.f};
    mfma64_bfA_hi(aggrB + base, wph + SLOT(10 + et), acc, bx);
    mfma64_bfA_hi(xnB + (size_t)(b * 2 + d_t) * N_ * C_, wph + SLOT(14 + et), acc, bx);
    __shared__ unsigned short tile[64][136];   // 17.4 KB, +8 pad
    const float* bias = agg_b + et * C_;
    const int wave = threadIdx.x >> 6, lane = threadIdx.x & 63;
    const int mloc = lane & 15, quad = lane >> 4;
#pragma unroll
    for (int r = 0; r < 4; ++r) {
        int lrow = wave * 16 + quad * 4 + r;
#pragma unroll
        for (int t = 0; t < 8; ++t) {
            int col = t * 16 + mloc;
            float v = acc[t][r] + bias[col];
            v = (v > 0.f) ? fast_tanh_pos(v) : 0.f;
            tile[lrow][col] = f2bf(v);
        }
    }
    __syncthreads();
    // vectorized tile -> outsB copy (16B coalesced stores)
    {
        int row0 = bx * 64;
#pragma unroll
        for (int it = 0; it < 4; ++it) {
            int chunk = it * 256 + threadIdx.x;       // 0..1023
            int row = chunk >> 4, c8 = (chunk & 15) * 8;
            int grow = row0 + row;
            if (grow < N_)
                *(us8*)(outsB + base + (size_t)grow * C_ + c8) = *(const us8*)&tile[row][c8];
        }
    }
    // second GEMM: klin[nt] on the tile (nt == d_t ; tt = et>=2), hi-only
    int nt = d_t, tt = (et >= 2) ? 1 : 0;
    ffrag acc2[8];
#pragma unroll
    for (int t = 0; t < 8; ++t) acc2[t] = (ffrag){0.f, 0.f, 0.f, 0.f};
    const unsigned short* Kh = wph + SLOT(18 + nt);
    int lr = wave * 16 + mloc;
#pragma unroll
    for (int s = 0; s < 4; ++s) {
        bfrag a0 = *(const bfrag*)&tile[lr][s * 32 + quad * 8];
        const unsigned short* pBh = Kh + ((size_t)s * 512 + lane) * 8;
#pragma unroll
        for (int t = 0; t < 8; ++t) {
            bfrag bh = *(const bfrag*)(pBh + (size_t)t * 512);
            acc2[t] = __builtin_amdgcn_mfma_f32_16x16x32_bf16(a0, bh, acc2[t], 0, 0, 0);
        }
    }
    __shared__ float cs[128];
    if (threadIdx.x < 128) cs[threadIdx.x] = 0.f;
    __syncthreads();
    const int rbase = bx * 64 + wave * 16 + quad * 4;
#pragma unroll
    for (int t = 0; t < 8; ++t) {
        int col = t * 16 + mloc;
        float bv = klin_b[nt * C_ + col];
        float s = 0.f;
#pragma unroll
        for (int r = 0; r < 4; ++r) {
            int row = rbase + r;
            if (row < N_) s += fast_tanh(acc2[t][r] + bv);
        }
        s += __shfl_xor(s, 16);
        s += __shfl_xor(s, 32);
        if (quad == 0) atomicAdd(&cs[col], s);
    }
    __syncthreads();
    if (threadIdx.x < 128)
        atomicAdd(&colsum[(size_t)((b * 2 + nt) * 2 + tt) * C_ + threadIdx.x], cs[threadIdx.x]);
    // last-block score fusion
    __shared__ int isLast;
    if (threadIdx.x == 0) {
        __threadfence();
        isLast = (atomicAdd(done, 1) == AGGK_BLOCKS - 1) ? 1 : 0;
    }
    __syncthreads();
    if (!isLast) return;
    __shared__ float red[2][2];
    for (int bnt = 0; bnt < 4; ++bnt) {
        int ntl = bnt & 1;
        float v0 = 0.f, v1l = 0.f;
        if (threadIdx.x < 128) {
            int c = threadIdx.x;
            float qc = q[ntl * C_ + c];
            float c0 = atomicAdd(&colsum[(size_t)(bnt * 2 + 0) * C_ + c], 0.f);
            float c1 = atomicAdd(&colsum[(size_t)(bnt * 2 + 1) * C_ + c], 0.f);
            v0 = qc * c0;
            v1l = qc * c1;
        }
#pragma unroll
        for (int m = 32; m > 0; m >>= 1) {
            v0 += __shfl_down(v0, m);
            v1l += __shfl_down(v1l, m);
        }
        if ((threadIdx.x & 63) == 0 && wave < 2) {
            red[wave][0] = v0;
            red[wave][1] = v1l;
        }
        __syncthreads();
        if (threadIdx.x == 0) {
            float s0 = (red[0][0] + red[1][0]) / (float)N_;
            float s1 = (red[0][1] + red[1][1]) / (float)N_;
            float mx = fmaxf(s0, s1);
            float e0 = __expf(s0 - mx), e1 = __expf(s1 - mx);
            float invd = 1.f / (e0 + e1);
            attn[bnt * 2 + 0] = e0 * invd;
            attn[bnt * 2 + 1] = e1 * invd;
        }
        __syncthreads();
    }
}

__global__ void output_kernel(const unsigned short* __restrict__ outsB,
                              const float* __restrict__ attn,
                              float* __restrict__ out)
{
    int idx = blockIdx.x * blockDim.x + threadIdx.x;
    int c4 = idx & 31;
    int row = idx >> 5;
    int b = row / TWO_N;
    int r = row % TWO_N;
    int nt = (r >= N_) ? 1 : 0;
    int n = r - nt * N_;
    int et0 = nt, et1 = 3 - nt;
    float a0 = attn[(b * 2 + nt) * 2 + 0];
    float a1 = attn[(b * 2 + nt) * 2 + 1];
    const ushort4* o0 = (const ushort4*)(outsB + ((size_t)(b * T_ + et0) * N_ + n) * C_);
    const ushort4* o1 = (const ushort4*)(outsB + ((size_t)(b * T_ + et1) * N_ + n) * C_);
    ushort4 u0 = o0[c4], u1 = o1[c4];
    float4 o;
    o.x = a0 * bf2f(u0.x) + a1 * bf2f(u1.x);
    o.y = a0 * bf2f(u0.y) + a1 * bf2f(u1.y);
    o.z = a0 * bf2f(u0.z) + a1 * bf2f(u1.z);
    o.w = a0 * bf2f(u0.w) + a1 * bf2f(u1.w);
    ((float4*)out)[idx] = o;
}

extern "C" void kernel_launch(void* const* d_in, const int* in_sizes, int n_in,
                              void* d_out, int out_size, void* d_ws, size_t ws_size,
                              hipStream_t stream)
{
    const float* x       = (const float*)d_in[0];
    const int*   eidx    = (const int*)d_in[1];
    const float* ew      = (const float*)d_in[2];
    const float* proj_w  = (const float*)d_in[3];
    const float* proj_b  = (const float*)d_in[4];
    const float* q       = (const float*)d_in[5];
    const float* klin_w  = (const float*)d_in[6];
    const float* klin_b  = (const float*)d_in[7];
    const float* lin_src = (const float*)d_in[8];
    const float* lin_dst = (const float*)d_in[9];
    const float* eproj_w = (const float*)d_in[10];
    const float* eproj_b = (const float*)d_in[11];
    const float* agg_w   = (const float*)d_in[12];
    const float* agg_b   = (const float*)d_in[13];
    const float* att_w   = (const float*)d_in[14];
    const float* att_b   = (const float*)d_in[15];

    float* ws = (float*)d_ws;
    size_t o = 0;
    float* xnBf   = ws + o; o += 1280000;   // xn bf16, live proj -> aggklin
    float* GU     = ws + o; o += 5120000;   // G (bf16, sy->aggregate) ∪ outsB (bf16)
    float* YiBf   = ws + o; o += 2560000;   // Yi bf16
    float* aggrBf = ws + o; o += 2560000;   // bf16 aggr
    float* pwqf   = ws + o; o += 2 * 8 * EP_;      // 1,310,720 (uint2 CSR entries)
    float* asrc   = ws + o; o += 40000;
    float* adst   = ws + o; o += 40000;
    float* v1     = ws + o; o += 512;
    float* bias_i = ws + o; o += 512;
    float* attn   = ws + o; o += 16;
    // zeroed-by-setup region (contiguous ints): count, cursor, colsum, done
    int*   count  = (int*)(ws + o); o += 40000;
    int*   cursor = (int*)(ws + o); o += 40000;
    float* colsum = ws + o; o += 1024;
    int*   done   = (int*)(ws + o); o += 4;
    int*   offs   = (int*)(ws + o); o += 40008;
    unsigned short* wph = (unsigned short*)(ws + o); o += 163840;
    unsigned short* wpl = (unsigned short*)(ws + o); o += 163840;
    unsigned short* lph = (unsigned short*)(ws + o); o += 1024;
    unsigned short* lpl = (unsigned short*)(ws + o); o += 1024;
    // total ≈ 13.4M floats ≈ 54 MB

    unsigned short* xnB   = (unsigned short*)xnBf;
    unsigned short* G     = (unsigned short*)GU;
    unsigned short* outsB = (unsigned short*)GU;
    unsigned short* YiB   = (unsigned short*)YiBf;
    unsigned short* aggrB = (unsigned short*)aggrBf;
    unsigned int*   pwq   = (unsigned int*)pwqf;

    setup_kernel<<<dim3(243), 256, 0, stream>>>(proj_w, att_w, agg_w, klin_w,
                                                lin_src, lin_dst, eproj_w, eproj_b,
                                                att_b, wph, wpl, lph, lpl,
                                                v1, bias_i, count);
    cp_kernel<<<dim3(672), 256, 0, stream>>>(eidx, count, x, wph, wpl, proj_b,
                                             lin_src, lin_dst, xnB, asrc, adst);
    scan_kernel<<<dim3(B_ * T_), 256, 0, stream>>>(count, offs, pwq);
    sy_kernel<<<dim3(1792), 256, 0, stream>>>(eidx, ew, asrc, adst, offs, cursor,
                                              pwq, xnB, wph, wpl, bias_i, G, YiB);
    aggregate_kernel<<<dim3(10000), 256, 0, stream>>>(G, YiB, v1, pwq, offs, aggrB);
    aggklin_kernel<<<dim3(AGGK_BLOCKS), 256, 0, stream>>>(aggrB, xnB, wph, agg_b,
                                                          klin_b, q, outsB, colsum,
                                                          done, attn);
    output_kernel<<<dim3(2500), 256, 0, stream>>>(outsB, attn, (float*)d_out);
}

// Round 15
// 257.647 us; speedup vs baseline: 1.0906x; 1.0073x over previous
//
#include <hip/hip_runtime.h>
#include <math.h>

// Problem constants (from reference setup_inputs)
#define B_    2
#define N_    5000
#define C_    128
#define E_    65536
#define T_    4
#define TWO_N 10000
#define EP_   81920   // padded CSR capacity per (et,b)

// edge types: (src,dst) node types = (0,0),(1,1),(0,1),(1,0)
// s_t = et & 1 ; d_t = ((et+1)>>1) & 1
// XCD-pin convention: pair be = b*4+et == blockIdx.x & 7 for every kernel
// touching per-pair edge data (count, scatter, yji, aggregate, aggklin).
// CSR entry (8 B): uint2 { p fp32 ; (q_bf16 << 16) | src_u16 }
// xn is kept ONLY as bf16 (xnB); nodedot fused on fp32 accumulators in cp.
// R13 lesson: these GEMMs are L2-weight-load bound, NOT occupancy bound.
// R14/R15: wherever the GEMM output is bf16-quantized anyway (aggklin, yji),
// drop the W-lo correction term — halves weight loads + MFMAs, error ~ output ulp.

__device__ __forceinline__ unsigned short f2bf(float f) {
    unsigned u = __float_as_uint(f);
    u += 0x7fffu + ((u >> 16) & 1u);   // RNE
    return (unsigned short)(u >> 16);
}
__device__ __forceinline__ float bf2f(unsigned short h) {
    return __uint_as_float(((unsigned)h) << 16);
}
// fast tanh via hw exp: ~6 ops vs ~25 for libm tanhf; error ~1e-6 (<< bf16 ulp)
__device__ __forceinline__ float fast_tanh_pos(float x) {   // x >= 0
    float e = __expf(-2.f * x);
    return __fdividef(1.f - e, 1.f + e);
}
__device__ __forceinline__ float fast_tanh(float x) {
    float a = fabsf(x);
    float e = __expf(-2.f * a);
    float t = __fdividef(1.f - e, 1.f + e);
    return copysignf(t, x);
}

typedef __attribute__((ext_vector_type(8))) short bfrag;   // 8 bf16
typedef __attribute__((ext_vector_type(4))) float ffrag;   // 4 fp32 acc
typedef __attribute__((ext_vector_type(8))) unsigned short us8;  // 16B bf16 chunk

__device__ __forceinline__ void split8(const float* __restrict__ p, bfrag& hi, bfrag& lo) {
#pragma unroll
    for (int j = 0; j < 8; ++j) {
        float v = p[j];
        unsigned short h = f2bf(v);
        hi[j] = (short)h;
        lo[j] = (short)f2bf(v - bf2f(h));
    }
}

// Weight slots (each 128x128, B-fragment packed):
// 0-1: proj ; 2-5: Wj[et] ; 6-9: Wi[et] ; 10-13: W1[et] ; 14-17: W2[et] ; 18-19: klin[nt]
#define SLOT(i) ((size_t)(i) * 16384)

__device__ __forceinline__ void zero_acc(ffrag (&acc)[2][8]) {
#pragma unroll
    for (int h = 0; h < 2; ++h)
#pragma unroll
        for (int t = 0; t < 8; ++t) acc[h][t] = (ffrag){0.f, 0.f, 0.f, 0.f};
}

// Split-bf16 MFMA GEMM core, K=128, 4 waves x 32 rows, N=128. fp32 A (cp only).
__device__ __forceinline__ void mfma128(const float* __restrict__ A,
                                        const unsigned short* __restrict__ Whi,
                                        const unsigned short* __restrict__ Wlo,
                                        ffrag (&acc)[2][8], int bx)
{
    const int wave = threadIdx.x >> 6, lane = threadIdx.x & 63;
    const int mloc = lane & 15, quad = lane >> 4;
    const int row0w = bx * 128 + wave * 32;
    int r0 = row0w + mloc;      if (r0 >= N_) r0 = N_ - 1;  // clamp, stores guarded
    int r1 = row0w + 16 + mloc; if (r1 >= N_) r1 = N_ - 1;
#pragma unroll
    for (int s = 0; s < 4; ++s) {
        bfrag a0h, a0l, a1h, a1l;
        split8(A + (size_t)r0 * C_ + s * 32 + quad * 8, a0h, a0l);
        split8(A + (size_t)r1 * C_ + s * 32 + quad * 8, a1h, a1l);
        const unsigned short* pBh = Whi + ((size_t)s * 512 + lane) * 8;
        const unsigned short* pBl = Wlo + ((size_t)s * 512 + lane) * 8;
#pragma unroll
        for (int t = 0; t < 8; ++t) {
            bfrag bh = *(const bfrag*)(pBh + (size_t)t * 512);
            bfrag bl = *(const bfrag*)(pBl + (size_t)t * 512);
            acc[0][t] = __builtin_amdgcn_mfma_f32_16x16x32_bf16(a0h, bh, acc[0][t], 0, 0, 0);
            acc[0][t] = __builtin_amdgcn_mfma_f32_16x16x32_bf16(a0l, bh, acc[0][t], 0, 0, 0);
            acc[0][t] = __builtin_amdgcn_mfma_f32_16x16x32_bf16(a0h, bl, acc[0][t], 0, 0, 0);
            acc[1][t] = __builtin_amdgcn_mfma_f32_16x16x32_bf16(a1h, bh, acc[1][t], 0, 0, 0);
            acc[1][t] = __builtin_amdgcn_mfma_f32_16x16x32_bf16(a1l, bh, acc[1][t], 0, 0, 0);
            acc[1][t] = __builtin_amdgcn_mfma_f32_16x16x32_bf16(a1h, bl, acc[1][t], 0, 0, 0);
        }
    }
}

// bf16-A half-width core, HI-ONLY weights: 4 of 8 n-tiles.
__device__ __forceinline__ void mfma128_half_bfA_hi(const unsigned short* __restrict__ A,
                                                    const unsigned short* __restrict__ Whi,
                                                    ffrag (&acc)[2][4], int bx, int half)
{
    const int wave = threadIdx.x >> 6, lane = threadIdx.x & 63;
    const int mloc = lane & 15, quad = lane >> 4;
    const int row0w = bx * 128 + wave * 32;
    int r0 = row0w + mloc;      if (r0 >= N_) r0 = N_ - 1;
    int r1 = row0w + 16 + mloc; if (r1 >= N_) r1 = N_ - 1;
#pragma unroll
    for (int s = 0; s < 4; ++s) {
        bfrag a0 = *(const bfrag*)(A + (size_t)r0 * C_ + s * 32 + quad * 8);
        bfrag a1 = *(const bfrag*)(A + (size_t)r1 * C_ + s * 32 + quad * 8);
        const unsigned short* pBh = Whi + ((size_t)s * 512 + (size_t)half * 256 + lane) * 8;
#pragma unroll
        for (int t = 0; t < 4; ++t) {
            bfrag bh = *(const bfrag*)(pBh + (size_t)t * 512);
            acc[0][t] = __builtin_amdgcn_mfma_f32_16x16x32_bf16(a0, bh, acc[0][t], 0, 0, 0);
            acc[1][t] = __builtin_amdgcn_mfma_f32_16x16x32_bf16(a1, bh, acc[1][t], 0, 0, 0);
        }
    }
}

// M=64 bf16-A core, HI-ONLY weights: D = A @ Wh.
__device__ __forceinline__ void mfma64_bfA_hi(const unsigned short* __restrict__ A,
                                              const unsigned short* __restrict__ Whi,
                                              ffrag (&acc)[8], int bx)
{
    const int wave = threadIdx.x >> 6, lane = threadIdx.x & 63;
    const int mloc = lane & 15, quad = lane >> 4;
    int r0 = bx * 64 + wave * 16 + mloc; if (r0 >= N_) r0 = N_ - 1;
#pragma unroll
    for (int s = 0; s < 4; ++s) {
        bfrag a0 = *(const bfrag*)(A + (size_t)r0 * C_ + s * 32 + quad * 8);
        const unsigned short* pBh = Whi + ((size_t)s * 512 + lane) * 8;
#pragma unroll
        for (int t = 0; t < 8; ++t) {
            bfrag bh = *(const bfrag*)(pBh + (size_t)t * 512);
            acc[t] = __builtin_amdgcn_mfma_f32_16x16x32_bf16(a0, bh, acc[t], 0, 0, 0);
        }
    }
}

#define ZN_ 81028   // count(40000) + cursor(40000) + colsum(1024) + done(4)

// setup: blocks [0,160) pack_w ; [160] pack_L ; [161,163) prep ; [163,243) zero
__global__ __launch_bounds__(256) void setup_kernel(
    const float* __restrict__ proj_w, const float* __restrict__ att_w,
    const float* __restrict__ agg_w, const float* __restrict__ klin_w,
    const float* __restrict__ lin_src, const float* __restrict__ lin_dst,
    const float* __restrict__ eproj_w, const float* __restrict__ eproj_b,
    const float* __restrict__ att_b,
    unsigned short* __restrict__ wh, unsigned short* __restrict__ wl,
    unsigned short* __restrict__ lph, unsigned short* __restrict__ lpl,
    float* __restrict__ v1, float* __restrict__ bias_i, int* __restrict__ zbase)
{
    int blk = blockIdx.x;
    if (blk < 160) {
        int wave = threadIdx.x >> 6, lane = threadIdx.x & 63;
        int unit = blk * 4 + wave;      // 0..639
        int id = unit >> 5;             // slot 0..19
        int st = unit & 31;
        int s = st >> 3, t = st & 7;
        const float* src;
        if (id < 2)       src = proj_w + (size_t)id * 16384;
        else if (id < 6)  src = att_w + (size_t)(id - 2) * 384 * C_;
        else if (id < 10) src = att_w + (size_t)(id - 6) * 384 * C_ + (size_t)128 * C_;
        else if (id < 14) src = agg_w + (size_t)(id - 10) * 256 * C_;
        else if (id < 18) src = agg_w + (size_t)(id - 14) * 256 * C_ + (size_t)128 * C_;
        else              src = klin_w + (size_t)(id - 18) * 16384;
        int mloc = lane & 15, quad = lane >> 4;
        size_t dbase = SLOT(id) + ((size_t)(s * 8 + t) * 64 + lane) * 8;
#pragma unroll
        for (int j = 0; j < 8; ++j) {
            float v = src[(size_t)(s * 32 + quad * 8 + j) * C_ + t * 16 + mloc];
            unsigned short h = f2bf(v);
            wh[dbase + j] = h;
            wl[dbase + j] = f2bf(v - bf2f(h));
        }
    } else if (blk == 160) {
        int s = threadIdx.x >> 6;       // wave = s (0..3)
        int lane = threadIdx.x & 63;
        int mloc = lane & 15, quad = lane >> 4;
        const float* vec = nullptr;
        if (mloc < 8) {
            int nt = mloc >> 2, idx = mloc & 3;
            if (idx == 0)      vec = lin_src + nt * C_;
            else if (idx == 1) vec = lin_src + (nt + 2) * C_;
            else if (idx == 2) vec = lin_dst + nt * C_;
            else               vec = lin_dst + (3 - nt) * C_;
        }
        size_t dbase = ((size_t)(s * 64) + lane) * 8;
#pragma unroll
        for (int j = 0; j < 8; ++j) {
            float v = vec ? vec[s * 32 + quad * 8 + j] : 0.f;
            unsigned short h = f2bf(v);
            lph[dbase + j] = h;
            lpl[dbase + j] = f2bf(v - bf2f(h));
        }
    } else if (blk < 163) {
        int et = (blk - 161) * 2 + (threadIdx.x >> 7);
        int c = threadIdx.x & 127;
        float s1 = 0.f, s0 = 0.f;
        for (int k = 0; k < 128; ++k) {
            float wv = att_w[(size_t)et * 384 * C_ + (size_t)(256 + k) * C_ + c];
            s1 = fmaf(eproj_w[et * C_ + k], wv, s1);
            s0 = fmaf(eproj_b[et * C_ + k], wv, s0);
        }
        v1[et * C_ + c] = s1;
        bias_i[et * C_ + c] = att_b[et * C_ + c] + s0;
    } else {
        int base = (blk - 163) * 1024 + threadIdx.x * 4;
#pragma unroll
        for (int j = 0; j < 4; ++j)
            if (base + j < ZN_) zbase[base + j] = 0;
    }
}

// count + proj(+nodedot) hybrid: blocks [0,512) count (XCD-pinned, 4 edges/thr) ;
// [512,672) proj (emits xnB bf16 + fused nodedot on fp32 accumulators)
__global__ __launch_bounds__(256) void cp_kernel(
    const int* __restrict__ eidx, int* __restrict__ count,
    const float* __restrict__ x,
    const unsigned short* __restrict__ wph, const unsigned short* __restrict__ wpl,
    const float* __restrict__ proj_b,
    const float* __restrict__ lin_src, const float* __restrict__ lin_dst,
    unsigned short* __restrict__ xnB, float* __restrict__ asrc, float* __restrict__ adst)
{
    int blk = blockIdx.x;
    if (blk < 512) {
        int be = blk & 7;             // XCD-pin: pair = b*4+et
        int et = be & 3, b = be >> 2;
        int t4 = (blk >> 3) * 256 + threadIdx.x;   // 0..16383
        size_t ebase = ((size_t)et * B_ + b) * 2 * E_;
        int4 d4 = *(const int4*)(eidx + ebase + E_ + 4 * t4);
        int* cp = count + (size_t)be * N_;
        atomicAdd(&cp[d4.x], 1);
        atomicAdd(&cp[d4.y], 1);
        atomicAdd(&cp[d4.z], 1);
        atomicAdd(&cp[d4.w], 1);
        return;
    }
    int pidx = blk - 512;             // 0..159
    int bx = pidx % 40;
    int nt = (pidx / 40) & 1;
    int b = pidx / 80;
    const float* A = x + ((size_t)b * TWO_N + (size_t)nt * N_) * C_;
    ffrag acc[2][8];
    zero_acc(acc);
    mfma128(A, wph + SLOT(nt), wpl + SLOT(nt), acc, bx);
    unsigned short* out = xnB + (size_t)(b * 2 + nt) * N_ * C_;
    const float* bias = proj_b + nt * C_;
    const int wave = threadIdx.x >> 6, lane = threadIdx.x & 63;
    const int mloc = lane & 15, quad = lane >> 4;
    const int rbase = bx * 128 + wave * 32 + quad * 4;
    // lin columns for the fused nodedot
    const float* lv0 = lin_src + nt * C_;
    const float* lv1 = lin_src + (2 + nt) * C_;
    const float* lv2 = lin_dst + nt * C_;
    const float* lv3 = lin_dst + (3 - nt) * C_;
    float linv[4][8];
#pragma unroll
    for (int t = 0; t < 8; ++t) {
        int col = t * 16 + mloc;
        linv[0][t] = lv0[col]; linv[1][t] = lv1[col];
        linv[2][t] = lv2[col]; linv[3][t] = lv3[col];
    }
    const int et0 = nt, et1 = 2 + nt, et2 = nt, et3 = 3 - nt;
#pragma unroll
    for (int h = 0; h < 2; ++h)
#pragma unroll
        for (int r = 0; r < 4; ++r) {
            int row = rbase + h * 16 + r;
            bool ok = (row < N_);
            float p0 = 0.f, p1 = 0.f, p2 = 0.f, p3 = 0.f;
#pragma unroll
            for (int t = 0; t < 8; ++t) {
                int col = t * 16 + mloc;
                float vv = acc[h][t][r] + bias[col];
                if (ok) out[(size_t)row * C_ + col] = f2bf(vv);
                p0 = fmaf(vv, linv[0][t], p0);
                p1 = fmaf(vv, linv[1][t], p1);
                p2 = fmaf(vv, linv[2][t], p2);
                p3 = fmaf(vv, linv[3][t], p3);
            }
#pragma unroll
            for (int m = 1; m < 16; m <<= 1) {
                p0 += __shfl_xor(p0, m);
                p1 += __shfl_xor(p1, m);
                p2 += __shfl_xor(p2, m);
                p3 += __shfl_xor(p3, m);
            }
            if (mloc == 0 && ok) {
                asrc[(size_t)(b * T_ + et0) * N_ + row] = p0;
                asrc[(size_t)(b * T_ + et1) * N_ + row] = p1;
                adst[(size_t)(b * T_ + et2) * N_ + row] = p2;
                adst[(size_t)(b * T_ + et3) * N_ + row] = p3;
            }
        }
}

// Exclusive scan of 4-aligned strides -> CSR offsets; zero pad slots.
__global__ __launch_bounds__(256) void scan_kernel(const int* __restrict__ count,
                                                   int* __restrict__ offs,
                                                   unsigned int* __restrict__ pwq)
{
    int be = blockIdx.x;
    const int* cnt = count + (size_t)be * N_;
    int* off = offs + (size_t)be * (N_ + 1);
    __shared__ int sums[256];
    int tid = threadIdx.x;
    const int chunk = (N_ + 255) / 256;  // 20
    int lo = tid * chunk, hi = min(lo + chunk, N_);
    int s = 0;
    for (int i = lo; i < hi; ++i) s += (cnt[i] + 3) & ~3;
    sums[tid] = s;
    __syncthreads();
    for (int d = 1; d < 256; d <<= 1) {
        int v = (tid >= d) ? sums[tid - d] : 0;
        __syncthreads();
        sums[tid] += v;
        __syncthreads();
    }
    int run = (tid > 0) ? sums[tid - 1] : 0;
    uint2* ep = (uint2*)pwq;
    for (int i = lo; i < hi; ++i) {
        off[i] = run;
        int c = cnt[i], pc = (c + 3) & ~3;
        for (int k = c; k < pc; ++k)
            ep[(size_t)be * EP_ + run + k] = make_uint2(0u, 0u);
        run += pc;
    }
    if (tid == 255) off[N_] = sums[255];
}

// scatter + yji hybrid: blocks [0,512) scatter (4 edges/thr) ; [512,1792) yji —
// both XCD-pinned by pair (blk & 7 == be).
// yji roles: 0 -> G = interleaved bf16 {Z=xs*(xs@Wj), xs} ; 1 -> Yi (bf16);
// each role split into col-halves (64 cols/block). HI-ONLY weights (R15).
__global__ __launch_bounds__(256) void sy_kernel(
    const int* __restrict__ eidx, const float* __restrict__ ew,
    const float* __restrict__ asrc, const float* __restrict__ adst,
    const int* __restrict__ offs, int* __restrict__ cursor,
    unsigned int* __restrict__ pwq,
    const unsigned short* __restrict__ xnB,
    const unsigned short* __restrict__ wph,
    const float* __restrict__ bias_i,
    unsigned short* __restrict__ G, unsigned short* __restrict__ YiB)
{
    int blk = blockIdx.x;
    if (blk < 512) {
        int be = blk & 7;             // XCD-pin
        int et = be & 3, b = be >> 2;
        int t4 = (blk >> 3) * 256 + threadIdx.x;   // 0..16383
        size_t ebase = ((size_t)et * B_ + b) * 2 * E_;
        int4 s4 = *(const int4*)(eidx + ebase + 4 * t4);
        int4 d4 = *(const int4*)(eidx + ebase + E_ + 4 * t4);
        float4 w4 = *(const float4*)(ew + ((size_t)et * B_ + b) * E_ + 4 * t4);
        const float* ap = asrc + (size_t)be * N_;
        const float* dp = adst + (size_t)be * N_;
        const int* op = offs + (size_t)be * (N_ + 1);
        int* cp = cursor + (size_t)be * N_;
        uint2* epb = (uint2*)pwq + (size_t)be * EP_;
#pragma unroll
        for (int j = 0; j < 4; ++j) {
            int src = (j == 0) ? s4.x : (j == 1) ? s4.y : (j == 2) ? s4.z : s4.w;
            int dst = (j == 0) ? d4.x : (j == 1) ? d4.y : (j == 2) ? d4.z : d4.w;
            float w = (j == 0) ? w4.x : (j == 1) ? w4.y : (j == 2) ? w4.z : w4.w;
            float al = ap[src] + dp[dst];
            al = (al > 0.f) ? al : 0.2f * al;
            float p = __expf(al);
            int pos = op[dst] + atomicAdd(&cp[dst], 1);
            unsigned int packed = (unsigned int)src | ((unsigned int)f2bf(p * w) << 16);
            epb[pos] = make_uint2(__float_as_uint(p), packed);
        }
        return;
    }
    int yidx = blk - 512;             // 0..1279 ; 512 % 8 == 0 keeps pin aligned
    int be = yidx & 7;                // XCD-pin
    int et = be & 3, b = be >> 2;
    int rest = yidx >> 3;             // 0..159
    int half = rest & 1;
    int role = (rest >> 1) & 1;
    int bx = rest >> 2;               // 0..39
    int s_t = et & 1, d_t = ((et + 1) >> 1) & 1;
    int ntsel = (role == 0) ? s_t : d_t;
    const unsigned short* A = xnB + (size_t)(b * 2 + ntsel) * N_ * C_;
    int slot = (role == 0) ? 2 + et : 6 + et;
    ffrag acc[2][4];
#pragma unroll
    for (int h = 0; h < 2; ++h)
#pragma unroll
        for (int t = 0; t < 4; ++t) acc[h][t] = (ffrag){0.f, 0.f, 0.f, 0.f};
    mfma128_half_bfA_hi(A, wph + SLOT(slot), acc, bx, half);
    const float* bias = bias_i + et * C_;
    const int wave = threadIdx.x >> 6, lane = threadIdx.x & 63;
    const int mloc = lane & 15, quad = lane >> 4;
    const int rbase = bx * 128 + wave * 32 + quad * 4;
#pragma unroll
    for (int h = 0; h < 2; ++h)
#pragma unroll
        for (int r = 0; r < 4; ++r) {
            int row = rbase + h * 16 + r;
            if (row >= N_) continue;
#pragma unroll
            for (int t = 0; t < 4; ++t) {
                int col = (half * 4 + t) * 16 + mloc;
                float v = acc[h][t][r];
                if (role == 0) {
                    float xv = bf2f(A[(size_t)row * C_ + col]);
                    *(ushort2*)(G + ((size_t)be * N_ + row) * 256 + 2 * col) =
                        make_ushort2(f2bf(v * xv), f2bf(xv));
                } else {
                    YiB[((size_t)be * N_ + row) * C_ + col] = f2bf(v + bias[col]);
                }
            }
        }
}

// Segment-softmax aggregation, one wave per (node, et, b), XCD-pinned by pair.
// aggr = (Σ p·Z[s] + Yi'⊙Σ p·xs + v1⊙Σ q·xs) / Σ p, emitted as bf16.
__global__ __launch_bounds__(256) void aggregate_kernel(
    const unsigned short* __restrict__ G, const unsigned short* __restrict__ YiB,
    const float* __restrict__ v1, const unsigned int* __restrict__ pwq,
    const int* __restrict__ offs, unsigned short* __restrict__ aggrB)
{
    int pair = blockIdx.x & 7;                       // = b*T_+et (XCD-pin)
    int n = (blockIdx.x >> 3) * 4 + (threadIdx.x >> 6);
    int et = pair & 3;
    int be = pair;
    int l = threadIdx.x & 63;
    const unsigned short* Gp = G + (size_t)be * N_ * 256;
    int beg = offs[(size_t)be * (N_ + 1) + n];
    int end = offs[(size_t)be * (N_ + 1) + n + 1];
    const unsigned int* ep = pwq + ((size_t)be * EP_ + beg) * 2;
    float a1x = 0.f, a1y = 0.f, a2x = 0.f, a2y = 0.f, a3x = 0.f, a3y = 0.f, denom = 0.f;
    int cnt = end - beg;  // multiple of 4; pads have p=q=0, src=0
    for (int i = 0; i < cnt; i += 4) {
        uint4 u01 = *(const uint4*)(ep + 2 * i);      // entries i, i+1
        uint4 u23 = *(const uint4*)(ep + 2 * i + 4);  // entries i+2, i+3
        float p0 = __uint_as_float(u01.x), q0 = bf2f((unsigned short)(u01.y >> 16));
        float p1 = __uint_as_float(u01.z), q1 = bf2f((unsigned short)(u01.w >> 16));
        float p2 = __uint_as_float(u23.x), q2 = bf2f((unsigned short)(u23.y >> 16));
        float p3 = __uint_as_float(u23.z), q3 = bf2f((unsigned short)(u23.w >> 16));
        int s0 = u01.y & 0xffff, s1 = u01.w & 0xffff;
        int s2 = u23.y & 0xffff, s3 = u23.w & 0xffff;
        ushort4 g0 = *(const ushort4*)(Gp + (size_t)s0 * 256 + 4 * l);
        ushort4 g1 = *(const ushort4*)(Gp + (size_t)s1 * 256 + 4 * l);
        ushort4 g2 = *(const ushort4*)(Gp + (size_t)s2 * 256 + 4 * l);
        ushort4 g3 = *(const ushort4*)(Gp + (size_t)s3 * 256 + 4 * l);
        denom += p0 + p1 + p2 + p3;
        a1x = fmaf(p0, bf2f(g0.x), a1x); a2x = fmaf(p0, bf2f(g0.y), a2x);
        a3x = fmaf(q0, bf2f(g0.y), a3x);
        a1y = fmaf(p0, bf2f(g0.z), a1y); a2y = fmaf(p0, bf2f(g0.w), a2y);
        a3y = fmaf(q0, bf2f(g0.w), a3y);
        a1x = fmaf(p1, bf2f(g1.x), a1x); a2x = fmaf(p1, bf2f(g1.y), a2x);
        a3x = fmaf(q1, bf2f(g1.y), a3x);
        a1y = fmaf(p1, bf2f(g1.z), a1y); a2y = fmaf(p1, bf2f(g1.w), a2y);
        a3y = fmaf(q1, bf2f(g1.w), a3y);
        a1x = fmaf(p2, bf2f(g2.x), a1x); a2x = fmaf(p2, bf2f(g2.y), a2x);
        a3x = fmaf(q2, bf2f(g2.y), a3x);
        a1y = fmaf(p2, bf2f(g2.z), a1y); a2y = fmaf(p2, bf2f(g2.w), a2y);
        a3y = fmaf(q2, bf2f(g2.w), a3y);
        a1x = fmaf(p3, bf2f(g3.x), a1x); a2x = fmaf(p3, bf2f(g3.y), a2x);
        a3x = fmaf(q3, bf2f(g3.y), a3x);
        a1y = fmaf(p3, bf2f(g3.z), a1y); a2y = fmaf(p3, bf2f(g3.w), a2y);
        a3y = fmaf(q3, bf2f(g3.w), a3y);
    }
    ushort2 yiu = *(const ushort2*)(YiB + ((size_t)be * N_ + n) * C_ + 2 * l);
    float2 vv = *(const float2*)(v1 + et * C_ + 2 * l);
    float inv = (denom > 0.f) ? 1.f / denom : 0.f;
    float ox = (a1x + bf2f(yiu.x) * a2x + vv.x * a3x) * inv;
    float oy = (a1y + bf2f(yiu.y) * a2y + vv.y * a3y) * inv;
    *(ushort2*)(aggrB + ((size_t)be * N_ + n) * C_ + 2 * l) = make_ushort2(f2bf(ox), f2bf(oy));
}

#define AGGK_BLOCKS 640

// Fused (M=64 tiles, hi-only weights): outs = tanh(relu(aggr@W1 + xnB[d_t]@W2
// + agg_b)) -> LDS tile -> vectorized copy to outsB; then klin GEMM on the
// tile -> colsum (quad-reduced); last block -> attn.
__global__ __launch_bounds__(256) void aggklin_kernel(
    const unsigned short* __restrict__ aggrB, const unsigned short* __restrict__ xnB,
    const unsigned short* __restrict__ wph,
    const float* __restrict__ agg_b, const float* __restrict__ klin_b,
    const float* __restrict__ q, unsigned short* __restrict__ outsB,
    float* __restrict__ colsum, int* __restrict__ done, float* __restrict__ attn)
{
    int blk = blockIdx.x;
    int be = blk & 7, bx = blk >> 3;   // XCD-pin by pair; bx 0..79 (M=64 tiles)
    int et = be & 3, b = be >> 2;
    int d_t = ((et + 1) >> 1) & 1;
    size_t base = (size_t)be * N_ * C_;
    ffrag acc[8];
#pragma unroll
    for (int t = 0; t < 8; ++t) acc[t] = (ffrag){0.f, 0.f, 0.f, 0.f};
    mfma64_bfA_hi(aggrB + base, wph + SLOT(10 + et), acc, bx);
    mfma64_bfA_hi(xnB + (size_t)(b * 2 + d_t) * N_ * C_, wph + SLOT(14 + et), acc, bx);
    __shared__ unsigned short tile[64][136];   // 17.4 KB, +8 pad
    const float* bias = agg_b + et * C_;
    const int wave = threadIdx.x >> 6, lane = threadIdx.x & 63;
    const int mloc = lane & 15, quad = lane >> 4;
#pragma unroll
    for (int r = 0; r < 4; ++r) {
        int lrow = wave * 16 + quad * 4 + r;
#pragma unroll
        for (int t = 0; t < 8; ++t) {
            int col = t * 16 + mloc;
            float v = acc[t][r] + bias[col];
            v = (v > 0.f) ? fast_tanh_pos(v) : 0.f;
            tile[lrow][col] = f2bf(v);
        }
    }
    __syncthreads();
    // vectorized tile -> outsB copy (16B coalesced stores)
    {
        int row0 = bx * 64;
#pragma unroll
        for (int it = 0; it < 4; ++it) {
            int chunk = it * 256 + threadIdx.x;       // 0..1023
            int row = chunk >> 4, c8 = (chunk & 15) * 8;
            int grow = row0 + row;
            if (grow < N_)
                *(us8*)(outsB + base + (size_t)grow * C_ + c8) = *(const us8*)&tile[row][c8];
        }
    }
    // second GEMM: klin[nt] on the tile (nt == d_t ; tt = et>=2), hi-only
    int nt = d_t, tt = (et >= 2) ? 1 : 0;
    ffrag acc2[8];
#pragma unroll
    for (int t = 0; t < 8; ++t) acc2[t] = (ffrag){0.f, 0.f, 0.f, 0.f};
    const unsigned short* Kh = wph + SLOT(18 + nt);
    int lr = wave * 16 + mloc;
#pragma unroll
    for (int s = 0; s < 4; ++s) {
        bfrag a0 = *(const bfrag*)&tile[lr][s * 32 + quad * 8];
        const unsigned short* pBh = Kh + ((size_t)s * 512 + lane) * 8;
#pragma unroll
        for (int t = 0; t < 8; ++t) {
            bfrag bh = *(const bfrag*)(pBh + (size_t)t * 512);
            acc2[t] = __builtin_amdgcn_mfma_f32_16x16x32_bf16(a0, bh, acc2[t], 0, 0, 0);
        }
    }
    __shared__ float cs[128];
    if (threadIdx.x < 128) cs[threadIdx.x] = 0.f;
    __syncthreads();
    const int rbase = bx * 64 + wave * 16 + quad * 4;
#pragma unroll
    for (int t = 0; t < 8; ++t) {
        int col = t * 16 + mloc;
        float bv = klin_b[nt * C_ + col];
        float s = 0.f;
#pragma unroll
        for (int r = 0; r < 4; ++r) {
            int row = rbase + r;
            if (row < N_) s += fast_tanh(acc2[t][r] + bv);
        }
        s += __shfl_xor(s, 16);
        s += __shfl_xor(s, 32);
        if (quad == 0) atomicAdd(&cs[col], s);
    }
    __syncthreads();
    if (threadIdx.x < 128)
        atomicAdd(&colsum[(size_t)((b * 2 + nt) * 2 + tt) * C_ + threadIdx.x], cs[threadIdx.x]);
    // last-block score fusion
    __shared__ int isLast;
    if (threadIdx.x == 0) {
        __threadfence();
        isLast = (atomicAdd(done, 1) == AGGK_BLOCKS - 1) ? 1 : 0;
    }
    __syncthreads();
    if (!isLast) return;
    __shared__ float red[2][2];
    for (int bnt = 0; bnt < 4; ++bnt) {
        int ntl = bnt & 1;
        float v0 = 0.f, v1l = 0.f;
        if (threadIdx.x < 128) {
            int c = threadIdx.x;
            float qc = q[ntl * C_ + c];
            float c0 = atomicAdd(&colsum[(size_t)(bnt * 2 + 0) * C_ + c], 0.f);
            float c1 = atomicAdd(&colsum[(size_t)(bnt * 2 + 1) * C_ + c], 0.f);
            v0 = qc * c0;
            v1l = qc * c1;
        }
#pragma unroll
        for (int m = 32; m > 0; m >>= 1) {
            v0 += __shfl_down(v0, m);
            v1l += __shfl_down(v1l, m);
        }
        if ((threadIdx.x & 63) == 0 && wave < 2) {
            red[wave][0] = v0;
            red[wave][1] = v1l;
        }
        __syncthreads();
        if (threadIdx.x == 0) {
            float s0 = (red[0][0] + red[1][0]) / (float)N_;
            float s1 = (red[0][1] + red[1][1]) / (float)N_;
            float mx = fmaxf(s0, s1);
            float e0 = __expf(s0 - mx), e1 = __expf(s1 - mx);
            float invd = 1.f / (e0 + e1);
            attn[bnt * 2 + 0] = e0 * invd;
            attn[bnt * 2 + 1] = e1 * invd;
        }
        __syncthreads();
    }
}

__global__ void output_kernel(const unsigned short* __restrict__ outsB,
                              const float* __restrict__ attn,
                              float* __restrict__ out)
{
    int idx = blockIdx.x * blockDim.x + threadIdx.x;
    int c4 = idx & 31;
    int row = idx >> 5;
    int b = row / TWO_N;
    int r = row % TWO_N;
    int nt = (r >= N_) ? 1 : 0;
    int n = r - nt * N_;
    int et0 = nt, et1 = 3 - nt;
    float a0 = attn[(b * 2 + nt) * 2 + 0];
    float a1 = attn[(b * 2 + nt) * 2 + 1];
    const ushort4* o0 = (const ushort4*)(outsB + ((size_t)(b * T_ + et0) * N_ + n) * C_);
    const ushort4* o1 = (const ushort4*)(outsB + ((size_t)(b * T_ + et1) * N_ + n) * C_);
    ushort4 u0 = o0[c4], u1 = o1[c4];
    float4 o;
    o.x = a0 * bf2f(u0.x) + a1 * bf2f(u1.x);
    o.y = a0 * bf2f(u0.y) + a1 * bf2f(u1.y);
    o.z = a0 * bf2f(u0.z) + a1 * bf2f(u1.z);
    o.w = a0 * bf2f(u0.w) + a1 * bf2f(u1.w);
    ((float4*)out)[idx] = o;
}

extern "C" void kernel_launch(void* const* d_in, const int* in_sizes, int n_in,
                              void* d_out, int out_size, void* d_ws, size_t ws_size,
                              hipStream_t stream)
{
    const float* x       = (const float*)d_in[0];
    const int*   eidx    = (const int*)d_in[1];
    const float* ew      = (const float*)d_in[2];
    const float* proj_w  = (const float*)d_in[3];
    const float* proj_b  = (const float*)d_in[4];
    const float* q       = (const float*)d_in[5];
    const float* klin_w  = (const float*)d_in[6];
    const float* klin_b  = (const float*)d_in[7];
    const float* lin_src = (const float*)d_in[8];
    const float* lin_dst = (const float*)d_in[9];
    const float* eproj_w = (const float*)d_in[10];
    const float* eproj_b = (const float*)d_in[11];
    const float* agg_w   = (const float*)d_in[12];
    const float* agg_b   = (const float*)d_in[13];
    const float* att_w   = (const float*)d_in[14];
    const float* att_b   = (const float*)d_in[15];

    float* ws = (float*)d_ws;
    size_t o = 0;
    float* xnBf   = ws + o; o += 1280000;   // xn bf16, live proj -> aggklin
    float* GU     = ws + o; o += 5120000;   // G (bf16, sy->aggregate) ∪ outsB (bf16)
    float* YiBf   = ws + o; o += 2560000;   // Yi bf16
    float* aggrBf = ws + o; o += 2560000;   // bf16 aggr
    float* pwqf   = ws + o; o += 2 * 8 * EP_;      // 1,310,720 (uint2 CSR entries)
    float* asrc   = ws + o; o += 40000;
    float* adst   = ws + o; o += 40000;
    float* v1     = ws + o; o += 512;
    float* bias_i = ws + o; o += 512;
    float* attn   = ws + o; o += 16;
    // zeroed-by-setup region (contiguous ints): count, cursor, colsum, done
    int*   count  = (int*)(ws + o); o += 40000;
    int*   cursor = (int*)(ws + o); o += 40000;
    float* colsum = ws + o; o += 1024;
    int*   done   = (int*)(ws + o); o += 4;
    int*   offs   = (int*)(ws + o); o += 40008;
    unsigned short* wph = (unsigned short*)(ws + o); o += 163840;
    unsigned short* wpl = (unsigned short*)(ws + o); o += 163840;
    unsigned short* lph = (unsigned short*)(ws + o); o += 1024;
    unsigned short* lpl = (unsigned short*)(ws + o); o += 1024;
    // total ≈ 13.4M floats ≈ 54 MB

    unsigned short* xnB   = (unsigned short*)xnBf;
    unsigned short* G     = (unsigned short*)GU;
    unsigned short* outsB = (unsigned short*)GU;
    unsigned short* YiB   = (unsigned short*)YiBf;
    unsigned short* aggrB = (unsigned short*)aggrBf;
    unsigned int*   pwq   = (unsigned int*)pwqf;

    setup_kernel<<<dim3(243), 256, 0, stream>>>(proj_w, att_w, agg_w, klin_w,
                                                lin_src, lin_dst, eproj_w, eproj_b,
                                                att_b, wph, wpl, lph, lpl,
                                                v1, bias_i, count);
    cp_kernel<<<dim3(672), 256, 0, stream>>>(eidx, count, x, wph, wpl, proj_b,
                                             lin_src, lin_dst, xnB, asrc, adst);
    scan_kernel<<<dim3(B_ * T_), 256, 0, stream>>>(count, offs, pwq);
    sy_kernel<<<dim3(1792), 256, 0, stream>>>(eidx, ew, asrc, adst, offs, cursor,
                                              pwq, xnB, wph, bias_i, G, YiB);
    aggregate_kernel<<<dim3(10000), 256, 0, stream>>>(G, YiB, v1, pwq, offs, aggrB);
    aggklin_kernel<<<dim3(AGGK_BLOCKS), 256, 0, stream>>>(aggrB, xnB, wph, agg_b,
                                                          klin_b, q, outsB, colsum,
                                                          done, attn);
    output_kernel<<<dim3(2500), 256, 0, stream>>>(outsB, attn, (float*)d_out);
}